// Round 2
// baseline (8637.836 us; speedup 1.0000x reference)
//
#include <hip/hip_runtime.h>
#include <hip/hip_bf16.h>
#include <math.h>

// Problem constants
#define Bb 32
#define Ss 1024
#define Dh 512

// GEMM epilogue flags
#define F_RELU  1
#define F_RESID 2
#define F_ROWSC 4   // v *= rsc[m]          (nsum / cnt)
#define F_SIMSC 8   // v *= rsc[m]*csc[n]   (cosine sim scaling)

__device__ __forceinline__ float wsum(float v) {
#pragma unroll
  for (int o = 32; o; o >>= 1) v += __shfl_xor(v, o);
  return v;
}
__device__ __forceinline__ float wmaxf(float v) {
#pragma unroll
  for (int o = 32; o; o >>= 1) v = fmaxf(v, __shfl_xor(v, o));
  return v;
}

// ---------------------------------------------------------------------------
// Generic fp32 tiled GEMM:  C[z] = epilogue(alpha * A[z] (·) B[z])
//   BT=true : C = A @ B^T  (A: MxK lda, B: NxK ldb)   -- torch-Linear layout
//   BT=false: C = A @ B    (A: MxK lda, B: KxN ldb)
// 128x128 tile, BK=16, 256 threads, 8x8 micro-tile per thread.
// ---------------------------------------------------------------------------
template<bool BT>
__global__ __launch_bounds__(256)
void gemm_k(const float* __restrict__ A, const float* __restrict__ Bm,
            const float* __restrict__ bias, const float* __restrict__ resid,
            const float* __restrict__ rsc, const float* __restrict__ csc,
            float* __restrict__ C,
            int M, int N, int K, int lda, int ldb, int ldc,
            long sA, long sB, long sC, int sS, float alpha, int flags)
{
  const int z = blockIdx.z;
  A  += (long)z * sA;
  Bm += (long)z * sB;
  C  += (long)z * sC;
  const float* rs = rsc ? rsc + (long)z * sS : nullptr;
  const float* cs = csc ? csc + (long)z * sS : nullptr;

  __shared__ float As[16][132];   // [k][m], padded
  __shared__ float Bs[16][132];   // [k][n]

  const int tid = threadIdx.x;
  const int tx = tid & 15, ty = tid >> 4;
  const int m0 = blockIdx.x * 128, n0 = blockIdx.y * 128;

  float acc[8][8];
#pragma unroll
  for (int i = 0; i < 8; ++i)
#pragma unroll
    for (int j = 0; j < 8; ++j) acc[i][j] = 0.f;

  const int arow = tid >> 2;          // 0..63
  const int akq  = (tid & 3) * 4;     // 0,4,8,12

  for (int k0 = 0; k0 < K; k0 += 16) {
    // --- A tile: 128 rows x 16 k ---
#pragma unroll
    for (int half = 0; half < 2; ++half) {
      int m  = arow + half * 64;
      int gm = m0 + m;
      float4 a4 = make_float4(0.f, 0.f, 0.f, 0.f);
      if (gm < M) a4 = *(const float4*)(A + (long)gm * lda + k0 + akq);
      As[akq + 0][m] = a4.x; As[akq + 1][m] = a4.y;
      As[akq + 2][m] = a4.z; As[akq + 3][m] = a4.w;
    }
    // --- B tile ---
    if (BT) {
#pragma unroll
      for (int half = 0; half < 2; ++half) {
        int n  = arow + half * 64;
        int gn = n0 + n;
        float4 b4 = make_float4(0.f, 0.f, 0.f, 0.f);
        if (gn < N) b4 = *(const float4*)(Bm + (long)gn * ldb + k0 + akq);
        Bs[akq + 0][n] = b4.x; Bs[akq + 1][n] = b4.y;
        Bs[akq + 2][n] = b4.z; Bs[akq + 3][n] = b4.w;
      }
    } else {
      int kr = tid >> 5;              // 0..7
      int nq = (tid & 31) * 4;        // 0..124
#pragma unroll
      for (int half = 0; half < 2; ++half) {
        int kk = kr + half * 8;
        int gn = n0 + nq;
        float4 b4 = make_float4(0.f, 0.f, 0.f, 0.f);
        if (gn < N) b4 = *(const float4*)(Bm + (long)(k0 + kk) * ldb + gn);
        *(float4*)&Bs[kk][nq] = b4;
      }
    }
    __syncthreads();

#pragma unroll
    for (int kk = 0; kk < 16; ++kk) {
      float a[8], b[8];
      *(float4*)&a[0] = *(const float4*)&As[kk][ty * 8];
      *(float4*)&a[4] = *(const float4*)&As[kk][ty * 8 + 4];
      *(float4*)&b[0] = *(const float4*)&Bs[kk][tx * 8];
      *(float4*)&b[4] = *(const float4*)&Bs[kk][tx * 8 + 4];
#pragma unroll
      for (int i = 0; i < 8; ++i)
#pragma unroll
        for (int j = 0; j < 8; ++j) acc[i][j] += a[i] * b[j];
    }
    __syncthreads();
  }

  // --- epilogue ---
#pragma unroll
  for (int i = 0; i < 8; ++i) {
    int gm = m0 + ty * 8 + i;
    if (gm >= M) continue;
#pragma unroll
    for (int j = 0; j < 8; ++j) {
      int gn = n0 + tx * 8 + j;
      if (gn >= N) continue;
      float v = acc[i][j] * alpha;
      if (flags & F_SIMSC) v *= rs[gm] * cs[gn];
      if (flags & F_ROWSC) v *= rs[gm];
      if (bias) v += bias[gn];
      if (flags & F_RESID) v += resid[(long)z * sC + (long)gm * ldc + gn];
      if (flags & F_RELU) v = fmaxf(v, 0.f);
      C[(long)gm * ldc + gn] = v;
    }
  }
}

// ---------------------------------------------------------------------------
// out = LN(a + b) * g + beta   (rows of 512)
// ---------------------------------------------------------------------------
__global__ __launch_bounds__(256)
void ln_add_k(const float* __restrict__ a, const float* __restrict__ b,
              const float* __restrict__ g, const float* __restrict__ be,
              float* __restrict__ out)
{
  long row = blockIdx.x;
  const float* pa = a + row * 512;
  const float* pb = b + row * 512;
  float* po = out + row * 512;
  int t = threadIdx.x;
  float v0 = pa[t] + pb[t];
  float v1 = pa[t + 256] + pb[t + 256];

  __shared__ float red[4], red2[4];
  float s = wsum(v0 + v1);
  if ((t & 63) == 0) red[t >> 6] = s;
  __syncthreads();
  float mean = (red[0] + red[1] + red[2] + red[3]) * (1.f / 512.f);
  float c0 = v0 - mean, c1 = v1 - mean;
  float ss = wsum(c0 * c0 + c1 * c1);
  if ((t & 63) == 0) red2[t >> 6] = ss;
  __syncthreads();
  float var = (red2[0] + red2[1] + red2[2] + red2[3]) * (1.f / 512.f);
  float rstd = rsqrtf(var + 1e-5f);
  po[t]       = c0 * rstd * g[t]       + be[t];
  po[t + 256] = c1 * rstd * g[t + 256] + be[t + 256];
}

// invn[row] = 1 / max(||x_row||, 1e-12), rows of 512
__global__ __launch_bounds__(256)
void rownorm_k(const float* __restrict__ x, float* __restrict__ invn)
{
  long row = blockIdx.x;
  const float* p = x + row * 512;
  int t = threadIdx.x;
  float v0 = p[t], v1 = p[t + 256];
  __shared__ float red[4];
  float s = wsum(v0 * v0 + v1 * v1);
  if ((t & 63) == 0) red[t >> 6] = s;
  __syncthreads();
  if (t == 0) {
    float tot = red[0] + red[1] + red[2] + red[3];
    invn[row] = 1.f / fmaxf(sqrtf(tot), 1e-12f);
  }
}

// row softmax over 1024 cols, in place
__global__ __launch_bounds__(256)
void softmax_k(float* __restrict__ sc)
{
  long row = blockIdx.x;
  float* p = sc + row * 1024;
  int t = threadIdx.x;
  float v[4];
#pragma unroll
  for (int i = 0; i < 4; ++i) v[i] = p[t + 256 * i];

  __shared__ float redm[4], redsum[4];
  float m4 = fmaxf(fmaxf(v[0], v[1]), fmaxf(v[2], v[3]));
  float wm = wmaxf(m4);
  if ((t & 63) == 0) redm[t >> 6] = wm;
  __syncthreads();
  float MX = fmaxf(fmaxf(redm[0], redm[1]), fmaxf(redm[2], redm[3]));
  float s = 0.f;
#pragma unroll
  for (int i = 0; i < 4; ++i) { v[i] = __expf(v[i] - MX); s += v[i]; }
  float ws_ = wsum(s);
  if ((t & 63) == 0) redsum[t >> 6] = ws_;
  __syncthreads();
  float inv = 1.f / (redsum[0] + redsum[1] + redsum[2] + redsum[3]);
#pragma unroll
  for (int i = 0; i < 4; ++i) p[t + 256 * i] = v[i] * inv;
}

// per-row top-4 (descending, ties -> lower index, matching lax.top_k)
__global__ __launch_bounds__(64)
void topk_k(const float* __restrict__ sim, int* __restrict__ idx4)
{
  long row = blockIdx.x;
  const float* p = sim + row * 1024;
  int t = threadIdx.x;
  int c0 = -1, c1 = -1, c2 = -1, c3 = -1;
#pragma unroll
  for (int pass = 0; pass < 4; ++pass) {
    float best = -INFINITY;
    int bi = 1 << 30;
    for (int j = t; j < 1024; j += 64) {
      if (j == c0 || j == c1 || j == c2 || j == c3) continue;
      float v = p[j];
      if (v > best || (v == best && j < bi)) { best = v; bi = j; }
    }
#pragma unroll
    for (int off = 32; off; off >>= 1) {
      float ov = __shfl_down(best, off);
      int   oi = __shfl_down(bi, off);
      if (ov > best || (ov == best && oi < bi)) { best = ov; bi = oi; }
    }
    bi = __shfl(bi, 0);
    if (pass == 0) c0 = bi; else if (pass == 1) c1 = bi;
    else if (pass == 2) c2 = bi; else c3 = bi;
  }
  if (t == 0) { int* q = idx4 + row * 4; q[0] = c0; q[1] = c1; q[2] = c2; q[3] = c3; }
}

// adjacency in place over a sim CHUNK (nb batches); idx4/invcnt are chunk-local
__global__ __launch_bounds__(256)
void adj_k(float* __restrict__ sim, const int* __restrict__ idx4,
           float* __restrict__ invcnt)
{
  long row = blockIdx.x;          // local: b*S + i within chunk
  int b = (int)(row >> 10);
  int i = (int)(row & 1023);
  float* prow = sim + row * 1024;
  const int* my = idx4 + row * 4;
  int m0 = my[0], m1 = my[1], m2 = my[2], m3 = my[3];
  int t = threadIdx.x;
  float lsum = 0.f;
  for (int j = t; j < 1024; j += 256) {
    float v = prow[j];
    bool present = false;
    if (j != i) {
      present = (j == m0) | (j == m1) | (j == m2) | (j == m3);
      if (!present) {
        const int* oj = idx4 + (((long)b << 10) + j) * 4;
        present = (oj[0] == i) | (oj[1] == i) | (oj[2] == i) | (oj[3] == i);
      }
    }
    float a = present ? v : 0.f;
    prow[j] = a;
    lsum += a;
  }
  __shared__ float red[4];
  float s = wsum(lsum);
  if ((t & 63) == 0) red[t >> 6] = s;
  __syncthreads();
  if (t == 0) {
    float tot = red[0] + red[1] + red[2] + red[3];
    invcnt[row] = 1.f / fmaxf(tot, 1.f);
  }
}

// pooled[b,d] = mean_s x2[b,s,d]
__global__ __launch_bounds__(256)
void pool_k(const float* __restrict__ x2, float* __restrict__ pooled)
{
  int i = blockIdx.x * 256 + threadIdx.x;   // 0..16383
  int b = i >> 9, d = i & 511;
  const float* p = x2 + (long)b * Ss * 512 + d;
  float s = 0.f;
  for (int sdx = 0; sdx < Ss; ++sdx) s += p[(long)sdx * 512];
  pooled[i] = s * (1.f / 1024.f);
}

// ---------------------------------------------------------------------------
static inline void gemm(hipStream_t st, bool bt,
                        const float* A, const float* Bm, const float* bias,
                        const float* resid, const float* rsc, const float* csc,
                        float* C, int M, int N, int K, int lda, int ldb, int ldc,
                        long sA, long sB, long sC, int sS, float alpha, int flags,
                        int nz)
{
  dim3 g((M + 127) / 128, (N + 127) / 128, nz), b(256);
  if (bt)
    gemm_k<true><<<g, b, 0, st>>>(A, Bm, bias, resid, rsc, csc, C, M, N, K,
                                  lda, ldb, ldc, sA, sB, sC, sS, alpha, flags);
  else
    gemm_k<false><<<g, b, 0, st>>>(A, Bm, bias, resid, rsc, csc, C, M, N, K,
                                   lda, ldb, ldc, sA, sB, sC, sS, alpha, flags);
}

extern "C" void kernel_launch(void* const* d_in, const int* in_sizes, int n_in,
                              void* d_out, int out_size, void* d_ws, size_t ws_size,
                              hipStream_t stream)
{
  (void)in_sizes; (void)n_in; (void)out_size;
  const float* x     = (const float*)d_in[0];
  const float* enc_w = (const float*)d_in[1];
  const float* enc_b = (const float*)d_in[2];
  const float* in_w  = (const float*)d_in[3];
  const float* in_b  = (const float*)d_in[4];
  const float* out_w = (const float*)d_in[5];
  const float* out_b = (const float*)d_in[6];
  const float* ln1_g = (const float*)d_in[7];
  const float* ln1_b = (const float*)d_in[8];
  const float* fw1   = (const float*)d_in[9];
  const float* fb1   = (const float*)d_in[10];
  const float* fw2   = (const float*)d_in[11];
  const float* fb2   = (const float*)d_in[12];
  const float* gc_w  = (const float*)d_in[13];
  const float* gc_b  = (const float*)d_in[14];
  const float* ln2_g = (const float*)d_in[15];
  const float* ln2_b = (const float*)d_in[16];
  const float* dec_w = (const float*)d_in[17];
  const float* dec_b = (const float*)d_in[18];
  float* out = (float*)d_out;

  // ---- arena: 3 x 64MB regions + ~1MB smalls = 193MB peak ----
  const long BIG = 16L * 1024 * 1024;            // 16M floats
  const long need_floats = 3 * BIG + 212992;
  if (ws_size < (size_t)need_floats * 4) return; // diagnostic: all-zero out

  float* R0 = (float*)d_ws;        // h -> nsum -> x2
  float* R1 = R0 + BIG;            // ctx -> x1
  float* R2 = R0 + 2 * BIG;        // scratch arena
  float* SM = R0 + 3 * BIG;
  float* invn   = SM;              // 32768
  float* invcnt = SM + 32768;      // 32768
  float* pooled = SM + 65536;      // 16384
  int*   idx4   = (int*)(SM + 98304); // 32768*4 ints

  float* h   = R0;
  float* ctx = R1;
  float* x1  = R1;

  const int Mtok = Bb * Ss;                // 32768

  // 1. h = relu(x @ enc_w^T + enc_b)
  gemm(stream, true, x, enc_w, enc_b, nullptr, nullptr, nullptr, h,
       Mtok, 512, 512, 512, 512, 512, 0, 0, 0, 0, 1.f, F_RELU, 1);

  // 2+3. attention, chunks of 4 batches; qkv chunk (24MB) + scores (32MB) in R2
  for (int c = 0; c < 8; ++c) {
    float* qkvc = R2;                      // 4096 x 1536
    float* scr  = R2 + 8L * 1024 * 1024;   // 4 x 2 x 1024 x 1024
    long row0 = (long)c * 4096;
    gemm(stream, true, h + row0 * 512, in_w, in_b, nullptr, nullptr, nullptr,
         qkvc, 4096, 1536, 512, 512, 512, 1536, 0, 0, 0, 0, 1.f, 0, 1);
    for (int hh = 0; hh < 2; ++hh) {
      gemm(stream, true,
           qkvc + hh * 256,                 // Q
           qkvc + 512 + hh * 256,           // K
           nullptr, nullptr, nullptr, nullptr,
           scr + (long)hh * Ss * Ss,
           1024, 1024, 256, 1536, 1536, 1024,
           (long)Ss * 1536, (long)Ss * 1536, 2L * Ss * Ss, 0,
           0.0625f, 0, 4);
    }
    softmax_k<<<dim3(8192), dim3(256), 0, stream>>>(scr);
    for (int hh = 0; hh < 2; ++hh) {
      gemm(stream, false,
           scr + (long)hh * Ss * Ss,
           qkvc + 1024 + hh * 256,          // V
           nullptr, nullptr, nullptr, nullptr,
           ctx + row0 * 512 + hh * 256,
           1024, 256, 1024, 1024, 1536, 512,
           2L * Ss * Ss, (long)Ss * 1536, (long)Ss * 512, 0,
           1.f, 0, 4);
    }
  }

  // 4+5. attn_out + LN1, row chunks of 8192 (x1 overwrites ctx per chunk)
  for (int r = 0; r < 4; ++r) {
    long row0 = (long)r * 8192;
    float* aoc = R2;                       // 8192 x 512
    gemm(stream, true, ctx + row0 * 512, out_w, out_b, nullptr, nullptr,
         nullptr, aoc, 8192, 512, 512, 512, 512, 512, 0, 0, 0, 0, 1.f, 0, 1);
    ln_add_k<<<dim3(8192), dim3(256), 0, stream>>>(h + row0 * 512, aoc,
                                                   ln1_g, ln1_b, x1 + row0 * 512);
  }

  // 6+7. FFN, row chunks of 8192; mid chunk (32MB) in R2
  for (int r = 0; r < 4; ++r) {
    long row0 = (long)r * 8192;
    float* midc = R2;                      // 8192 x 1024
    gemm(stream, true, x1 + row0 * 512, fw1, fb1, nullptr, nullptr, nullptr,
         midc, 8192, 1024, 512, 512, 512, 1024, 0, 0, 0, 0, 1.f, F_RELU, 1);
    gemm(stream, true, midc, fw2, fb2, x1 + row0 * 512, nullptr, nullptr,
         x1 + row0 * 512, 8192, 512, 1024, 1024, 1024, 512,
         0, 0, 0, 0, 1.f, F_RESID, 1);
  }

  // 8. row norms of x1
  rownorm_k<<<dim3(Mtok), dim3(256), 0, stream>>>(x1, invn);

  // 9-12. sim/topk/adj/nsum, chunks of 8 batches; sim chunk (32MB) in R2
  float* nsum = R0;                        // h dead after LN1
  for (int g = 0; g < 4; ++g) {
    long b0 = (long)g * 8;
    long row0 = b0 * Ss;                   // g*8192
    float* simc = R2;                      // 8 x 1024 x 1024
    gemm(stream, true, x1 + row0 * 512, x1 + row0 * 512, nullptr, nullptr,
         invn + row0, invn + row0, simc,
         1024, 1024, 512, 512, 512, 1024,
         (long)Ss * 512, (long)Ss * 512, (long)Ss * Ss, 1024, 1.f, F_SIMSC, 8);
    topk_k<<<dim3(8192), dim3(64), 0, stream>>>(simc, idx4 + row0 * 4);
    adj_k<<<dim3(8192), dim3(256), 0, stream>>>(simc, idx4 + row0 * 4,
                                                invcnt + row0);
    gemm(stream, false, simc, x1 + row0 * 512, nullptr, nullptr,
         invcnt + row0, nullptr, nsum + row0 * 512,
         1024, 512, 1024, 1024, 512, 512,
         (long)Ss * Ss, (long)Ss * 512, (long)Ss * 512, 1024, 1.f, F_ROWSC, 8);
  }

  // 13/14. gcout = x1 @ gc_w[:,:512]^T + gc_b ; gcout += nsum @ gc_w[:,512:]^T
  float* gcout = R2;                       // 32768 x 512
  gemm(stream, true, x1, gc_w, gc_b, nullptr, nullptr, nullptr, gcout,
       Mtok, 512, 512, 512, 1024, 512, 0, 0, 0, 0, 1.f, 0, 1);
  gemm(stream, true, nsum, gc_w + 512, nullptr, gcout, nullptr, nullptr, gcout,
       Mtok, 512, 512, 512, 1024, 512, 0, 0, 0, 0, 1.f, F_RESID, 1);

  // 15. x2 = LN(x1 + gcout)  (overwrites nsum region)
  float* x2 = R0;
  ln_add_k<<<dim3(Mtok), dim3(256), 0, stream>>>(x1, gcout, ln2_g, ln2_b, x2);

  // 16. pool over S
  pool_k<<<dim3(64), dim3(256), 0, stream>>>(x2, pooled);

  // 17. out = pooled @ dec_w^T + dec_b
  gemm(stream, true, pooled, dec_w, dec_b, nullptr, nullptr, nullptr, out,
       Bb, 512, 512, 512, 512, 512, 0, 0, 0, 0, 1.f, 0, 1);
}

// Round 3
// 3798.518 us; speedup vs baseline: 2.2740x; 2.2740x over previous
//
#include <hip/hip_runtime.h>
#include <hip/hip_bf16.h>
#include <math.h>

typedef unsigned short u16;
typedef __attribute__((ext_vector_type(8))) short bfrag;   // 8 bf16 (4 VGPR)
typedef __attribute__((ext_vector_type(4))) float facc;    // 4 fp32 acc
typedef const __attribute__((address_space(1))) void* gaddr_t;
typedef __attribute__((address_space(3))) void* laddr_t;

#define F_RELU  1
#define F_RESID 2
#define F_ROWSC 4
#define F_SIMSC 8
#define F_ACC   16

__device__ __forceinline__ u16 f2bf(float f) {
  __hip_bfloat16 h = __float2bfloat16(f);
  return *reinterpret_cast<u16*>(&h);
}
__device__ __forceinline__ float bf2f(u16 u) {
  __hip_bfloat16 h = *reinterpret_cast<__hip_bfloat16*>(&u);
  return __bfloat162float(h);
}
__device__ __forceinline__ float wsum(float v) {
#pragma unroll
  for (int o = 32; o; o >>= 1) v += __shfl_xor(v, o);
  return v;
}
__device__ __forceinline__ float wmaxf(float v) {
#pragma unroll
  for (int o = 32; o; o >>= 1) v = fmaxf(v, __shfl_xor(v, o));
  return v;
}

// ---------------------------------------------------------------------------
// bf16 MFMA GEMM:  C[z] = epilogue(alpha * A[z] @ B[z]^T)
// A: [M x K] bf16 (lda), B: [N x K] bf16 (ldb). M%128==0, N%128==0, K%32==0.
// 256 thr = 4 waves; tile 128x128; BK=32; wave = 64x64 (4x4 of 16x16x32 MFMA).
// LDS XOR-swizzle: slot (row, g) holds global k-group g ^ ((row>>1)&3).
// ---------------------------------------------------------------------------
__global__ __launch_bounds__(256)
void bgemm_k(const u16* __restrict__ A, const u16* __restrict__ B,
             const float* __restrict__ bias, const float* __restrict__ resid,
             const float* __restrict__ rsc, const float* __restrict__ csc,
             float* __restrict__ Cf, u16* __restrict__ Cb,
             int K, int lda, int ldb, int ldc,
             long sA, long sB, long sC, int sS,
             float alpha, int flags, int Mstore)
{
  const int z = blockIdx.z;
  A += (long)z * sA;
  B += (long)z * sB;
  const long cofs = (long)z * sC;
  const float* rs = rsc ? rsc + (long)z * sS : nullptr;
  const float* cs = csc ? csc + (long)z * sS : nullptr;

  __shared__ u16 As[128 * 32];
  __shared__ u16 Bs[128 * 32];

  const int tid  = threadIdx.x;
  const int wave = tid >> 6, lane = tid & 63;
  const int m0 = blockIdx.x * 128, n0 = blockIdx.y * 128;
  const int wrow = (wave >> 1) * 64, wcol = (wave & 1) * 64;

  // staging: wave stages rows [wave*32, wave*32+32) of A-tile and B-tile,
  // as two 16-row (1KB) global_load_lds instructions each.
  const int seg0 = wave * 32, seg1 = seg0 + 16;
  const int lrow = lane >> 2;          // 0..15
  const int lgrp = lane & 3;           // 0..3 (8-elem k-group)
  const int g0 = lgrp ^ (((seg0 + lrow) >> 1) & 3);
  const int g1 = lgrp ^ (((seg1 + lrow) >> 1) & 3);
  const u16* ga0 = A + (long)(m0 + seg0 + lrow) * lda + g0 * 8;
  const u16* ga1 = A + (long)(m0 + seg1 + lrow) * lda + g1 * 8;
  const u16* gb0 = B + (long)(n0 + seg0 + lrow) * ldb + g0 * 8;
  const u16* gb1 = B + (long)(n0 + seg1 + lrow) * ldb + g1 * 8;
  u16* la0 = As + seg0 * 32;
  u16* la1 = As + seg1 * 32;
  u16* lb0 = Bs + seg0 * 32;
  u16* lb1 = Bs + seg1 * 32;

  facc acc[4][4];
#pragma unroll
  for (int i = 0; i < 4; ++i)
#pragma unroll
    for (int j = 0; j < 4; ++j) acc[i][j] = (facc)(0.f);

  const int r16 = lane & 15, gq = lane >> 4;

  for (int k0 = 0; k0 < K; k0 += 32) {
    __builtin_amdgcn_global_load_lds((gaddr_t)(const void*)(ga0 + k0), (laddr_t)la0, 16, 0, 0);
    __builtin_amdgcn_global_load_lds((gaddr_t)(const void*)(ga1 + k0), (laddr_t)la1, 16, 0, 0);
    __builtin_amdgcn_global_load_lds((gaddr_t)(const void*)(gb0 + k0), (laddr_t)lb0, 16, 0, 0);
    __builtin_amdgcn_global_load_lds((gaddr_t)(const void*)(gb1 + k0), (laddr_t)lb1, 16, 0, 0);
    __syncthreads();

    bfrag af[4], bb[4];
#pragma unroll
    for (int mt = 0; mt < 4; ++mt) {
      int r = wrow + mt * 16 + r16;
      af[mt] = *(const bfrag*)&As[r * 32 + (gq ^ ((r >> 1) & 3)) * 8];
    }
#pragma unroll
    for (int nt = 0; nt < 4; ++nt) {
      int r = wcol + nt * 16 + r16;
      bb[nt] = *(const bfrag*)&Bs[r * 32 + (gq ^ ((r >> 1) & 3)) * 8];
    }
#pragma unroll
    for (int mt = 0; mt < 4; ++mt)
#pragma unroll
      for (int nt = 0; nt < 4; ++nt)
        acc[mt][nt] = __builtin_amdgcn_mfma_f32_16x16x32_bf16(af[mt], bb[nt], acc[mt][nt], 0, 0, 0);
    __syncthreads();
  }

  // epilogue: C/D layout col = lane&15, row = (lane>>4)*4 + reg
#pragma unroll
  for (int mt = 0; mt < 4; ++mt) {
#pragma unroll
    for (int nt = 0; nt < 4; ++nt) {
#pragma unroll
      for (int r = 0; r < 4; ++r) {
        int gm = m0 + wrow + mt * 16 + gq * 4 + r;
        int gn = n0 + wcol + nt * 16 + r16;
        if (gm >= Mstore) continue;
        float v = acc[mt][nt][r] * alpha;
        long ci = cofs + (long)gm * ldc + gn;
        if (flags & F_ACC)   v += Cf[ci];
        if (flags & F_SIMSC) v *= rs[gm] * cs[gn];
        if (flags & F_ROWSC) v *= rs[gm];
        if (bias)            v += bias[gn];
        if (flags & F_RESID) v += resid[ci];
        if (flags & F_RELU)  v = fmaxf(v, 0.f);
        if (Cf) Cf[ci] = v;
        if (Cb) Cb[ci] = f2bf(v);
      }
    }
  }
}

// ---------------------------------------------------------------------------
__global__ __launch_bounds__(256)
void castbf_k(const float* __restrict__ in, u16* __restrict__ out, int n)
{
  int i = blockIdx.x * 256 + threadIdx.x;
  if (i < n) out[i] = f2bf(in[i]);
}

// lo = x - bf16(x), as bf16
__global__ __launch_bounds__(256)
void x1lo_k(const float* __restrict__ xf, u16* __restrict__ lo, int n)
{
  int i = blockIdx.x * 256 + threadIdx.x;
  if (i < n) {
    float f = xf[i];
    lo[i] = f2bf(f - bf2f(f2bf(f)));
  }
}

// x1 = LN(bf16 a + f32 b); writes fp32 + bf16 (ob may alias a)
__global__ __launch_bounds__(256)
void ln1_k(const u16* __restrict__ a, const float* __restrict__ b,
           const float* __restrict__ g, const float* __restrict__ be,
           float* __restrict__ of, u16* __restrict__ ob)
{
  long row = blockIdx.x;
  long base = row * 512;
  int t = threadIdx.x;
  float v0 = bf2f(a[base + t])       + b[base + t];
  float v1 = bf2f(a[base + t + 256]) + b[base + t + 256];
  __shared__ float red[4], red2[4];
  float s = wsum(v0 + v1);
  if ((t & 63) == 0) red[t >> 6] = s;
  __syncthreads();
  float mean = (red[0] + red[1] + red[2] + red[3]) * (1.f / 512.f);
  float c0 = v0 - mean, c1 = v1 - mean;
  float ss = wsum(c0 * c0 + c1 * c1);
  if ((t & 63) == 0) red2[t >> 6] = ss;
  __syncthreads();
  float var = (red2[0] + red2[1] + red2[2] + red2[3]) * (1.f / 512.f);
  float rstd = rsqrtf(var + 1e-5f);
  float o0 = c0 * rstd * g[t]       + be[t];
  float o1 = c1 * rstd * g[t + 256] + be[t + 256];
  of[base + t] = o0;       of[base + t + 256] = o1;
  ob[base + t] = f2bf(o0); ob[base + t + 256] = f2bf(o1);
}

// x2 = LN(f32 a + f32 b) -> bf16 only
__global__ __launch_bounds__(256)
void ln2_k(const float* __restrict__ a, const float* __restrict__ b,
           const float* __restrict__ g, const float* __restrict__ be,
           u16* __restrict__ ob)
{
  long row = blockIdx.x;
  long base = row * 512;
  int t = threadIdx.x;
  float v0 = a[base + t] + b[base + t];
  float v1 = a[base + t + 256] + b[base + t + 256];
  __shared__ float red[4], red2[4];
  float s = wsum(v0 + v1);
  if ((t & 63) == 0) red[t >> 6] = s;
  __syncthreads();
  float mean = (red[0] + red[1] + red[2] + red[3]) * (1.f / 512.f);
  float c0 = v0 - mean, c1 = v1 - mean;
  float ss = wsum(c0 * c0 + c1 * c1);
  if ((t & 63) == 0) red2[t >> 6] = ss;
  __syncthreads();
  float var = (red2[0] + red2[1] + red2[2] + red2[3]) * (1.f / 512.f);
  float rstd = rsqrtf(var + 1e-5f);
  ob[base + t]       = f2bf(c0 * rstd * g[t]       + be[t]);
  ob[base + t + 256] = f2bf(c1 * rstd * g[t + 256] + be[t + 256]);
}

__global__ __launch_bounds__(256)
void rownorm_k(const float* __restrict__ x, float* __restrict__ invn)
{
  long row = blockIdx.x;
  const float* p = x + row * 512;
  int t = threadIdx.x;
  float v0 = p[t], v1 = p[t + 256];
  __shared__ float red[4];
  float s = wsum(v0 * v0 + v1 * v1);
  if ((t & 63) == 0) red[t >> 6] = s;
  __syncthreads();
  if (t == 0) {
    float tot = red[0] + red[1] + red[2] + red[3];
    invn[row] = 1.f / fmaxf(sqrtf(tot), 1e-12f);
  }
}

// row softmax over 1024 fp32 -> bf16 out
__global__ __launch_bounds__(256)
void softmaxbf_k(const float* __restrict__ sc, u16* __restrict__ pb)
{
  long row = blockIdx.x;
  const float* p = sc + row * 1024;
  u16* q = pb + row * 1024;
  int t = threadIdx.x;
  float v[4];
#pragma unroll
  for (int i = 0; i < 4; ++i) v[i] = p[t + 256 * i];
  __shared__ float redm[4], redsum[4];
  float m4 = fmaxf(fmaxf(v[0], v[1]), fmaxf(v[2], v[3]));
  float wm = wmaxf(m4);
  if ((t & 63) == 0) redm[t >> 6] = wm;
  __syncthreads();
  float MX = fmaxf(fmaxf(redm[0], redm[1]), fmaxf(redm[2], redm[3]));
  float s = 0.f;
#pragma unroll
  for (int i = 0; i < 4; ++i) { v[i] = __expf(v[i] - MX); s += v[i]; }
  float ws_ = wsum(s);
  if ((t & 63) == 0) redsum[t >> 6] = ws_;
  __syncthreads();
  float inv = 1.f / (redsum[0] + redsum[1] + redsum[2] + redsum[3]);
#pragma unroll
  for (int i = 0; i < 4; ++i) q[t + 256 * i] = f2bf(v[i] * inv);
}

// 64x64 tiled u16 transpose: out[z][c][r] = in[z][r][c]
__global__ __launch_bounds__(256)
void transp_k(const u16* __restrict__ in, u16* __restrict__ out,
              int inStride, int outStride, long sIn, long sOut)
{
  const int z = blockIdx.z;
  const int r0 = blockIdx.x * 64, c0 = blockIdx.y * 64;
  __shared__ u16 tile[64][66];
  const int t = threadIdx.x;
#pragma unroll
  for (int p = 0; p < 16; ++p) {
    int idx = p * 256 + t;
    int r = idx >> 6, c = idx & 63;
    tile[r][c] = in[(long)z * sIn + (long)(r0 + r) * inStride + c0 + c];
  }
  __syncthreads();
#pragma unroll
  for (int p = 0; p < 16; ++p) {
    int idx = p * 256 + t;
    int c = idx >> 6, r = idx & 63;
    out[(long)z * sOut + (long)(c0 + c) * outStride + r0 + r] = tile[r][c];
  }
}

// per-row top-4 (descending, ties -> lower index, matching lax.top_k)
__global__ __launch_bounds__(64)
void topk_k(const float* __restrict__ sim, int* __restrict__ idx4)
{
  long row = blockIdx.x;
  const float* p = sim + row * 1024;
  int t = threadIdx.x;
  int c0 = -1, c1 = -1, c2 = -1, c3 = -1;
#pragma unroll
  for (int pass = 0; pass < 4; ++pass) {
    float best = -INFINITY;
    int bi = 1 << 30;
    for (int j = t; j < 1024; j += 64) {
      if (j == c0 || j == c1 || j == c2 || j == c3) continue;
      float v = p[j];
      if (v > best || (v == best && j < bi)) { best = v; bi = j; }
    }
#pragma unroll
    for (int off = 32; off; off >>= 1) {
      float ov = __shfl_down(best, off);
      int   oi = __shfl_down(bi, off);
      if (ov > best || (ov == best && oi < bi)) { best = ov; bi = oi; }
    }
    bi = __shfl(bi, 0);
    if (pass == 0) c0 = bi; else if (pass == 1) c1 = bi;
    else if (pass == 2) c2 = bi; else c3 = bi;
  }
  if (t == 0) { int* q = idx4 + row * 4; q[0] = c0; q[1] = c1; q[2] = c2; q[3] = c3; }
}

// adjacency -> bf16 + invcnt (fp32 row-sum), from fp32 sim chunk
__global__ __launch_bounds__(256)
void adjbf_k(const float* __restrict__ sim, const int* __restrict__ idx4,
             u16* __restrict__ adjb, float* __restrict__ invcnt)
{
  long row = blockIdx.x;          // local: b*S + i within chunk
  int b = (int)(row >> 10);
  int i = (int)(row & 1023);
  const float* prow = sim + row * 1024;
  u16* arow_ = adjb + row * 1024;
  const int* my = idx4 + row * 4;
  int m0 = my[0], m1 = my[1], m2 = my[2], m3 = my[3];
  int t = threadIdx.x;
  float lsum = 0.f;
  for (int j = t; j < 1024; j += 256) {
    float v = prow[j];
    bool present = false;
    if (j != i) {
      present = (j == m0) | (j == m1) | (j == m2) | (j == m3);
      if (!present) {
        const int* oj = idx4 + (((long)b << 10) + j) * 4;
        present = (oj[0] == i) | (oj[1] == i) | (oj[2] == i) | (oj[3] == i);
      }
    }
    float a = present ? v : 0.f;
    arow_[j] = f2bf(a);
    lsum += a;
  }
  __shared__ float red[4];
  float s = wsum(lsum);
  if ((t & 63) == 0) red[t >> 6] = s;
  __syncthreads();
  if (t == 0) {
    float tot = red[0] + red[1] + red[2] + red[3];
    invcnt[row] = 1.f / fmaxf(tot, 1.f);
  }
}

// pooled_bf[128][512]: rows<32 = mean_s x2_bf, rows>=32 = 0 (pad for GEMM)
__global__ __launch_bounds__(256)
void poolbf_k(const u16* __restrict__ x2, u16* __restrict__ pooled)
{
  int i = blockIdx.x * 256 + threadIdx.x;   // 0..65535
  int b = i >> 9, d = i & 511;
  float s = 0.f;
  if (b < 32) {
    const u16* p = x2 + ((long)b << 10) * 512 + d;
    for (int sdx = 0; sdx < 1024; ++sdx) s += bf2f(p[(long)sdx * 512]);
    s *= (1.f / 1024.f);
  }
  pooled[i] = f2bf(s);
}

// ---------------------------------------------------------------------------
static inline void bgemm(hipStream_t st, const u16* A, const u16* B,
                         const float* bias, const float* resid,
                         const float* rsc, const float* csc,
                         float* Cf, u16* Cb, int M, int N, int K,
                         int lda, int ldb, int ldc,
                         long sA, long sB, long sC, int sS,
                         float alpha, int flags, int nz, int Mstore = -1)
{
  dim3 g(M / 128, N / 128, nz);
  bgemm_k<<<g, 256, 0, st>>>(A, B, bias, resid, rsc, csc, Cf, Cb, K,
                             lda, ldb, ldc, sA, sB, sC, sS, alpha, flags,
                             Mstore < 0 ? M : Mstore);
}

extern "C" void kernel_launch(void* const* d_in, const int* in_sizes, int n_in,
                              void* d_out, int out_size, void* d_ws, size_t ws_size,
                              hipStream_t stream)
{
  (void)in_sizes; (void)n_in; (void)out_size;
  const float* x     = (const float*)d_in[0];
  const float* enc_w = (const float*)d_in[1];
  const float* enc_b = (const float*)d_in[2];
  const float* in_w  = (const float*)d_in[3];
  const float* in_b  = (const float*)d_in[4];
  const float* out_w = (const float*)d_in[5];
  const float* out_b = (const float*)d_in[6];
  const float* ln1_g = (const float*)d_in[7];
  const float* ln1_b = (const float*)d_in[8];
  const float* fw1   = (const float*)d_in[9];
  const float* fb1   = (const float*)d_in[10];
  const float* fw2   = (const float*)d_in[11];
  const float* fb2   = (const float*)d_in[12];
  const float* gc_w  = (const float*)d_in[13];
  const float* gc_b  = (const float*)d_in[14];
  const float* ln2_g = (const float*)d_in[15];
  const float* ln2_b = (const float*)d_in[16];
  const float* dec_w = (const float*)d_in[17];
  const float* dec_b = (const float*)d_in[18];
  float* out = (float*)d_out;

  // ---- arena (floats), ~190.9 MB total ----
  const long MF = 1L << 20;
  float* ws  = (float*)d_ws;
  float* x1f = ws;                         // 16M floats: x1 fp32
  float* scr = ws + 16 * MF;               // 14M floats scratch
  u16*  bf1  = (u16*)(ws + 30 * MF);       // 16M u16: h_bf -> x1_bf (in place)
  u16*  bf2  = (u16*)(ws + 38 * MF);       // 16M u16: ctx_bf -> x1_lo -> nsum_bf
  u16*  wgt  = (u16*)(ws + 46 * MF);       // bf16 weights, 3145728 u16
  u16* encw = wgt;
  u16* inw  = wgt + 262144;
  u16* outw = wgt + 1048576;
  u16* fw1b = wgt + 1310720;
  u16* fw2b = wgt + 1835008;
  u16* gcwb = wgt + 2359296;
  u16* decw = wgt + 2883584;
  float* smallf = ws + 46 * MF + 1572864;
  float* invn    = smallf;                 // 32768
  float* invcnt  = smallf + 32768;         // 32768
  u16*   pooledb = (u16*)(smallf + 65536); // 65536 u16 (128x512, padded)
  int*   idx4    = (int*)(smallf + 98304); // 131072 ints
  const long need_bytes = (long)(46 * MF + 1572864 + 98304 + 131072) * 4;
  if (ws_size < (size_t)need_bytes) return;

  const int Mtok = 32768;

  // ---- casts: x + weights -> bf16 ----
  u16* xbf = (u16*)scr;                    // 16M u16 = 8M floats
  castbf_k<<<65536, 256, 0, stream>>>(x, xbf, 16777216);
  castbf_k<<<1024, 256, 0, stream>>>(enc_w, encw, 262144);
  castbf_k<<<3072, 256, 0, stream>>>(in_w,  inw,  786432);
  castbf_k<<<1024, 256, 0, stream>>>(out_w, outw, 262144);
  castbf_k<<<2048, 256, 0, stream>>>(fw1,   fw1b, 524288);
  castbf_k<<<2048, 256, 0, stream>>>(fw2,   fw2b, 524288);
  castbf_k<<<2048, 256, 0, stream>>>(gc_w,  gcwb, 524288);
  castbf_k<<<1024, 256, 0, stream>>>(dec_w, decw, 262144);

  // 1. h_bf = relu(x @ enc_w^T + enc_b)          [bf1]
  bgemm(stream, xbf, encw, enc_b, nullptr, nullptr, nullptr,
        nullptr, bf1, Mtok, 512, 512, 512, 512, 512, 0, 0, 0, 0, 1.f, F_RELU, 1);

  // 2+3. attention: 16 chunks x 2 batches
  for (int c = 0; c < 16; ++c) {
    long row0 = (long)c * 2048;
    u16*   qkvc = (u16*)scr;               // 2048x1536 u16
    float* scc  = scr + 2 * MF;            // [2][2][1024][1024] f32
    u16*   Pus  = (u16*)(scr + 6 * MF);    // same layout u16
    u16*   vT   = (u16*)(scr + 8 * MF);    // [2][2][256][1024] u16
    bgemm(stream, bf1 + row0 * 512, inw, in_b, nullptr, nullptr, nullptr,
          nullptr, qkvc, 2048, 1536, 512, 512, 512, 1536, 0, 0, 0, 0, 1.f, 0, 1);
    for (int h = 0; h < 2; ++h)
      bgemm(stream, qkvc + h * 256, qkvc + 512 + h * 256, nullptr, nullptr,
            nullptr, nullptr, scc + (long)h * 1048576, nullptr,
            1024, 1024, 256, 1536, 1536, 1024,
            1024L * 1536, 1024L * 1536, 2097152, 0, 0.0625f, 0, 2);
    softmaxbf_k<<<4096, 256, 0, stream>>>(scc, Pus);
    for (int h = 0; h < 2; ++h)
      transp_k<<<dim3(16, 4, 2), 256, 0, stream>>>(
          qkvc + 1024 + h * 256, vT + h * 262144, 1536, 1024,
          1024L * 1536, 524288);
    for (int h = 0; h < 2; ++h)
      bgemm(stream, Pus + (long)h * 1048576, vT + h * 262144, nullptr, nullptr,
            nullptr, nullptr, nullptr, bf2 + row0 * 512 + h * 256,
            1024, 256, 1024, 1024, 1024, 512,
            2097152, 524288, 524288, 0, 1.f, 0, 2);
  }

  // 4+5. attn_out + LN1 (x1_bf overwrites h_bf in place), 4 chunks
  for (int r = 0; r < 4; ++r) {
    long row0 = (long)r * 8192;
    float* aoc = scr;                      // 8192x512 f32
    bgemm(stream, bf2 + row0 * 512, outw, out_b, nullptr, nullptr, nullptr,
          aoc, nullptr, 8192, 512, 512, 512, 512, 512, 0, 0, 0, 0, 1.f, 0, 1);
    ln1_k<<<8192, 256, 0, stream>>>(bf1 + row0 * 512, aoc, ln1_g, ln1_b,
                                    x1f + row0 * 512, bf1 + row0 * 512);
  }

  // 6+7. FFN, 4 chunks
  for (int r = 0; r < 4; ++r) {
    long row0 = (long)r * 8192;
    u16* mid = (u16*)scr;                  // 8192x1024 u16
    bgemm(stream, bf1 + row0 * 512, fw1b, fb1, nullptr, nullptr, nullptr,
          nullptr, mid, 8192, 1024, 512, 512, 512, 1024, 0, 0, 0, 0, 1.f, F_RELU, 1);
    bgemm(stream, mid, fw2b, fb2, x1f + row0 * 512, nullptr, nullptr,
          x1f + row0 * 512, bf1 + row0 * 512, 8192, 512, 1024,
          1024, 1024, 512, 0, 0, 0, 0, 1.f, F_RESID, 1);
  }

  // 8. row norms; x1_lo for split-precision sim
  rownorm_k<<<Mtok, 256, 0, stream>>>(x1f, invn);
  x1lo_k<<<65536, 256, 0, stream>>>(x1f, bf2, 16777216);   // bf2 = x1_lo

  // 9-12. graph: 4 chunks x 8 batches
  for (int g = 0; g < 4; ++g) {
    long row0 = (long)g * 8192;
    float* simc = scr;                     // 8M f32
    u16*   adjb = (u16*)(scr + 8 * MF);    // 8M u16
    u16*   x1T  = (u16*)(scr + 12 * MF);   // [8][512][1024] u16
    // sim = (hi+lo)(hi+lo)^T (lo.lo dropped), scaled by invn_i*invn_j
    bgemm(stream, bf1 + row0 * 512, bf1 + row0 * 512, nullptr, nullptr,
          nullptr, nullptr, simc, nullptr, 1024, 1024, 512, 512, 512, 1024,
          524288, 524288, 1048576, 0, 1.f, 0, 8);
    bgemm(stream, bf1 + row0 * 512, bf2 + row0 * 512, nullptr, nullptr,
          nullptr, nullptr, simc, nullptr, 1024, 1024, 512, 512, 512, 1024,
          524288, 524288, 1048576, 0, 1.f, F_ACC, 8);
    bgemm(stream, bf2 + row0 * 512, bf1 + row0 * 512, nullptr, nullptr,
          invn + row0, invn + row0, simc, nullptr, 1024, 1024, 512, 512, 512, 1024,
          524288, 524288, 1048576, 1024, 1.f, F_ACC | F_SIMSC, 8);
    topk_k<<<8192, 64, 0, stream>>>(simc, idx4 + row0 * 4);
    adjbf_k<<<8192, 256, 0, stream>>>(simc, idx4 + row0 * 4, adjb, invcnt + row0);
    transp_k<<<dim3(16, 8, 8), 256, 0, stream>>>(bf1 + row0 * 512, x1T,
                                                 512, 1024, 524288, 524288);
    // nsum_bf (overwrites x1_lo rows of this chunk, row-aligned -> safe)
    bgemm(stream, adjb, x1T, nullptr, nullptr, invcnt + row0, nullptr,
          nullptr, bf2 + row0 * 512, 1024, 512, 1024, 1024, 1024, 512,
          1048576, 524288, 524288, 1024, 1.f, F_ROWSC, 8);
  }

  // 13-15. graph-conv + LN2, 4 chunks
  u16* x2us = (u16*)(scr + 4 * MF);        // 32768x512 u16
  for (int r = 0; r < 4; ++r) {
    long row0 = (long)r * 8192;
    float* gch = scr;                      // 8192x512 f32
    bgemm(stream, bf1 + row0 * 512, gcwb, gc_b, nullptr, nullptr, nullptr,
          gch, nullptr, 8192, 512, 512, 512, 1024, 512, 0, 0, 0, 0, 1.f, 0, 1);
    bgemm(stream, bf2 + row0 * 512, gcwb + 512, nullptr, nullptr, nullptr, nullptr,
          gch, nullptr, 8192, 512, 512, 512, 1024, 512, 0, 0, 0, 0, 1.f, F_ACC, 1);
    ln2_k<<<8192, 256, 0, stream>>>(x1f + row0 * 512, gch, ln2_g, ln2_b,
                                    x2us + row0 * 512);
  }

  // 16+17. pool + decoder (M padded to 128, store only 32 rows)
  poolbf_k<<<256, 256, 0, stream>>>(x2us, pooledb);
  bgemm(stream, pooledb, decw, dec_b, nullptr, nullptr, nullptr,
        out, nullptr, 128, 512, 512, 512, 512, 512, 0, 0, 0, 0, 1.f, 0, 1, 32);
}

// Round 4
// 2045.168 us; speedup vs baseline: 4.2235x; 1.8573x over previous
//
#include <hip/hip_runtime.h>
#include <hip/hip_bf16.h>
#include <math.h>

typedef unsigned short u16;
typedef __attribute__((ext_vector_type(8))) short bfrag;   // 8 bf16 (4 VGPR)
typedef __attribute__((ext_vector_type(4))) float facc;    // 4 fp32 acc
typedef const __attribute__((address_space(1))) void* gaddr_t;
typedef __attribute__((address_space(3))) void* laddr_t;

#define F_RELU   1
#define F_RESID  2   // += fp32 resid
#define F_ROWSC  4   // *= rsc[m]
#define F_SIMSC  8   // *= rsc[m]*csc[n]
#define F_ACC    16  // += Cf (before scaling)
#define F_RESID2 32  // += bf16 residH + residL

__device__ __forceinline__ u16 f2bf(float f) {
  __hip_bfloat16 h = __float2bfloat16(f);
  return *reinterpret_cast<u16*>(&h);
}
__device__ __forceinline__ float bf2f(u16 u) {
  __hip_bfloat16 h = *reinterpret_cast<__hip_bfloat16*>(&u);
  return __bfloat162float(h);
}
__device__ __forceinline__ float wsum(float v) {
#pragma unroll
  for (int o = 32; o; o >>= 1) v += __shfl_xor(v, o);
  return v;
}
__device__ __forceinline__ float wmaxf(float v) {
#pragma unroll
  for (int o = 32; o; o >>= 1) v = fmaxf(v, __shfl_xor(v, o));
  return v;
}

// ---------------------------------------------------------------------------
// bf16 MFMA GEMM with up to two K-segments:
//   C[z] = epi(alpha * (A1@B1^T [K1] + A2@B2^T [K2]))
// A: [M x K] bf16, B: [N x K] bf16. M%128==0, N%128==0, K%32==0.
// 256 thr = 4 waves; tile 128x128; BK=32; wave = 64x64 (4x4 of 16x16x32).
// LDS XOR swizzle: slot (row,g) holds global k-group g ^ ((row>>1)&3).
// ---------------------------------------------------------------------------
__global__ __launch_bounds__(256)
void bgemm_k(const u16* __restrict__ A, const u16* __restrict__ A2,
             const u16* __restrict__ B, const u16* __restrict__ B2,
             const float* __restrict__ bias, const float* __restrict__ resid,
             const u16* __restrict__ residH, const u16* __restrict__ residL,
             const float* __restrict__ rsc, const float* __restrict__ csc,
             float* __restrict__ Cf, u16* __restrict__ Cb, u16* __restrict__ Cb2,
             int K1, int K2, int lda, int lda2, int ldb, int ldb2, int ldc,
             long sA, long sA2, long sB, long sB2, long sC, int sS,
             float alpha, int flags, int Mstore)
{
  const int z = blockIdx.z;
  A += (long)z * sA;
  B += (long)z * sB;
  if (A2) A2 += (long)z * sA2;
  if (B2) B2 += (long)z * sB2;
  const long cofs = (long)z * sC;
  const float* rs = rsc ? rsc + (long)z * sS : nullptr;
  const float* cs = csc ? csc + (long)z * sS : nullptr;

  __shared__ u16 As[128 * 32];
  __shared__ u16 Bs[128 * 32];

  const int tid  = threadIdx.x;
  const int wave = tid >> 6, lane = tid & 63;
  const int m0 = blockIdx.x * 128, n0 = blockIdx.y * 128;
  const int wrow = (wave >> 1) * 64, wcol = (wave & 1) * 64;

  // staging: wave stages rows [wave*32, wave*32+32), two 16-row 1KB insts each
  const int sr0 = wave * 32, sr1 = sr0 + 16;
  const int lrow = lane >> 2;          // 0..15
  const int lgrp = lane & 3;           // 0..3
  const int g0 = lgrp ^ (((sr0 + lrow) >> 1) & 3);
  const int g1 = lgrp ^ (((sr1 + lrow) >> 1) & 3);
  u16* la0 = As + sr0 * 32;
  u16* la1 = As + sr1 * 32;
  u16* lb0 = Bs + sr0 * 32;
  u16* lb1 = Bs + sr1 * 32;

  facc acc[4][4];
#pragma unroll
  for (int i = 0; i < 4; ++i)
#pragma unroll
    for (int j = 0; j < 4; ++j) acc[i][j] = (facc)(0.f);

  const int r16 = lane & 15, gq = lane >> 4;

  for (int seg = 0; seg < 2; ++seg) {
    const int Ks = seg ? K2 : K1;
    if (Ks == 0) continue;
    const u16* Asrc = seg ? A2 : A;
    const u16* Bsrc = seg ? B2 : B;
    const int  la   = seg ? lda2 : lda;
    const int  lb   = seg ? ldb2 : ldb;
    const u16* ga0 = Asrc + (long)(m0 + sr0 + lrow) * la + g0 * 8;
    const u16* ga1 = Asrc + (long)(m0 + sr1 + lrow) * la + g1 * 8;
    const u16* gb0 = Bsrc + (long)(n0 + sr0 + lrow) * lb + g0 * 8;
    const u16* gb1 = Bsrc + (long)(n0 + sr1 + lrow) * lb + g1 * 8;

    for (int k0 = 0; k0 < Ks; k0 += 32) {
      __builtin_amdgcn_global_load_lds((gaddr_t)(const void*)(ga0 + k0), (laddr_t)la0, 16, 0, 0);
      __builtin_amdgcn_global_load_lds((gaddr_t)(const void*)(ga1 + k0), (laddr_t)la1, 16, 0, 0);
      __builtin_amdgcn_global_load_lds((gaddr_t)(const void*)(gb0 + k0), (laddr_t)lb0, 16, 0, 0);
      __builtin_amdgcn_global_load_lds((gaddr_t)(const void*)(gb1 + k0), (laddr_t)lb1, 16, 0, 0);
      __syncthreads();

      bfrag af[4], bb[4];
#pragma unroll
      for (int mt = 0; mt < 4; ++mt) {
        int r = wrow + mt * 16 + r16;
        af[mt] = *(const bfrag*)&As[r * 32 + (gq ^ ((r >> 1) & 3)) * 8];
      }
#pragma unroll
      for (int nt = 0; nt < 4; ++nt) {
        int r = wcol + nt * 16 + r16;
        bb[nt] = *(const bfrag*)&Bs[r * 32 + (gq ^ ((r >> 1) & 3)) * 8];
      }
#pragma unroll
      for (int mt = 0; mt < 4; ++mt)
#pragma unroll
        for (int nt = 0; nt < 4; ++nt)
          acc[mt][nt] = __builtin_amdgcn_mfma_f32_16x16x32_bf16(af[mt], bb[nt], acc[mt][nt], 0, 0, 0);
      __syncthreads();
    }
  }

  // epilogue: C/D layout col = lane&15, row = (lane>>4)*4 + reg
#pragma unroll
  for (int mt = 0; mt < 4; ++mt) {
#pragma unroll
    for (int nt = 0; nt < 4; ++nt) {
#pragma unroll
      for (int r = 0; r < 4; ++r) {
        int gm = m0 + wrow + mt * 16 + gq * 4 + r;
        int gn = n0 + wcol + nt * 16 + r16;
        if (gm >= Mstore) continue;
        float v = acc[mt][nt][r] * alpha;
        long ci = cofs + (long)gm * ldc + gn;
        if (flags & F_ACC)    v += Cf[ci];
        if (flags & F_SIMSC)  v *= rs[gm] * cs[gn];
        if (flags & F_ROWSC)  v *= rs[gm];
        if (bias)             v += bias[gn];
        if (flags & F_RESID)  v += resid[ci];
        if (flags & F_RESID2) v += bf2f(residH[ci]) + bf2f(residL[ci]);
        if (flags & F_RELU)   v = fmaxf(v, 0.f);
        if (Cf) Cf[ci] = v;
        if (Cb) {
          u16 hv = f2bf(v);
          Cb[ci] = hv;
          if (Cb2) Cb2[ci] = f2bf(v - bf2f(hv));
        }
      }
    }
  }
}

// ---------------------------------------------------------------------------
__global__ __launch_bounds__(256)
void castbf_k(const float* __restrict__ in, u16* __restrict__ out, int n)
{
  int i = blockIdx.x * 256 + threadIdx.x;
  if (i < n) out[i] = f2bf(in[i]);
}

// x1 = LN(bf16 a + f32 b) -> hi (in place over a ok) + lo
__global__ __launch_bounds__(256)
void ln1_k(const u16* __restrict__ a, const float* __restrict__ b,
           const float* __restrict__ g, const float* __restrict__ be,
           u16* __restrict__ oh, u16* __restrict__ ol)
{
  long base = (long)blockIdx.x * 512;
  int t = threadIdx.x;
  float v0 = bf2f(a[base + t])       + b[base + t];
  float v1 = bf2f(a[base + t + 256]) + b[base + t + 256];
  __shared__ float red[4], red2[4];
  float s = wsum(v0 + v1);
  if ((t & 63) == 0) red[t >> 6] = s;
  __syncthreads();
  float mean = (red[0] + red[1] + red[2] + red[3]) * (1.f / 512.f);
  float c0 = v0 - mean, c1 = v1 - mean;
  float ss = wsum(c0 * c0 + c1 * c1);
  if ((t & 63) == 0) red2[t >> 6] = ss;
  __syncthreads();
  float var = (red2[0] + red2[1] + red2[2] + red2[3]) * (1.f / 512.f);
  float rstd = rsqrtf(var + 1e-5f);
  float o0 = c0 * rstd * g[t]       + be[t];
  float o1 = c1 * rstd * g[t + 256] + be[t + 256];
  u16 h0 = f2bf(o0), h1 = f2bf(o1);
  oh[base + t] = h0;       oh[base + t + 256] = h1;
  ol[base + t] = f2bf(o0 - bf2f(h0));
  ol[base + t + 256] = f2bf(o1 - bf2f(h1));
}

// x2 = LN((hi+lo) + f32 b) -> bf16
__global__ __launch_bounds__(256)
void ln2_k(const u16* __restrict__ hi, const u16* __restrict__ lo,
           const float* __restrict__ b, const float* __restrict__ g,
           const float* __restrict__ be, u16* __restrict__ ob)
{
  long base = (long)blockIdx.x * 512;
  int t = threadIdx.x;
  float v0 = bf2f(hi[base + t])       + bf2f(lo[base + t])       + b[base + t];
  float v1 = bf2f(hi[base + t + 256]) + bf2f(lo[base + t + 256]) + b[base + t + 256];
  __shared__ float red[4], red2[4];
  float s = wsum(v0 + v1);
  if ((t & 63) == 0) red[t >> 6] = s;
  __syncthreads();
  float mean = (red[0] + red[1] + red[2] + red[3]) * (1.f / 512.f);
  float c0 = v0 - mean, c1 = v1 - mean;
  float ss = wsum(c0 * c0 + c1 * c1);
  if ((t & 63) == 0) red2[t >> 6] = ss;
  __syncthreads();
  float var = (red2[0] + red2[1] + red2[2] + red2[3]) * (1.f / 512.f);
  float rstd = rsqrtf(var + 1e-5f);
  ob[base + t]       = f2bf(c0 * rstd * g[t]       + be[t]);
  ob[base + t + 256] = f2bf(c1 * rstd * g[t + 256] + be[t + 256]);
}

// invn[row] = 1/max(||hi+lo||, 1e-12)
__global__ __launch_bounds__(256)
void rownorm_k(const u16* __restrict__ hi, const u16* __restrict__ lo,
               float* __restrict__ invn)
{
  long base = (long)blockIdx.x * 512;
  int t = threadIdx.x;
  float v0 = bf2f(hi[base + t])       + bf2f(lo[base + t]);
  float v1 = bf2f(hi[base + t + 256]) + bf2f(lo[base + t + 256]);
  __shared__ float red[4];
  float s = wsum(v0 * v0 + v1 * v1);
  if ((t & 63) == 0) red[t >> 6] = s;
  __syncthreads();
  if (t == 0) {
    float tot = red[0] + red[1] + red[2] + red[3];
    invn[blockIdx.x] = 1.f / fmaxf(sqrtf(tot), 1e-12f);
  }
}

// row softmax over 1024 fp32 -> bf16
__global__ __launch_bounds__(256)
void softmaxbf_k(const float* __restrict__ sc, u16* __restrict__ pb)
{
  long row = blockIdx.x;
  const float* p = sc + row * 1024;
  u16* q = pb + row * 1024;
  int t = threadIdx.x;
  float v[4];
#pragma unroll
  for (int i = 0; i < 4; ++i) v[i] = p[t + 256 * i];
  __shared__ float redm[4], redsum[4];
  float m4 = fmaxf(fmaxf(v[0], v[1]), fmaxf(v[2], v[3]));
  float wm = wmaxf(m4);
  if ((t & 63) == 0) redm[t >> 6] = wm;
  __syncthreads();
  float MX = fmaxf(fmaxf(redm[0], redm[1]), fmaxf(redm[2], redm[3]));
  float s = 0.f;
#pragma unroll
  for (int i = 0; i < 4; ++i) { v[i] = __expf(v[i] - MX); s += v[i]; }
  float ws_ = wsum(s);
  if ((t & 63) == 0) redsum[t >> 6] = ws_;
  __syncthreads();
  float inv = 1.f / (redsum[0] + redsum[1] + redsum[2] + redsum[3]);
#pragma unroll
  for (int i = 0; i < 4; ++i) q[t + 256 * i] = f2bf(v[i] * inv);
}

// 64x64 tiled u16 transpose: out[z][c][r] = in[z][r][c]
__global__ __launch_bounds__(256)
void transp_k(const u16* __restrict__ in, u16* __restrict__ out,
              int inStride, int outStride, long sIn, long sOut)
{
  const int z = blockIdx.z;
  const int r0 = blockIdx.x * 64, c0 = blockIdx.y * 64;
  __shared__ u16 tile[64][66];
  const int t = threadIdx.x;
#pragma unroll
  for (int p = 0; p < 16; ++p) {
    int idx = p * 256 + t;
    int r = idx >> 6, c = idx & 63;
    tile[r][c] = in[(long)z * sIn + (long)(r0 + r) * inStride + c0 + c];
  }
  __syncthreads();
#pragma unroll
  for (int p = 0; p < 16; ++p) {
    int idx = p * 256 + t;
    int c = idx >> 6, r = idx & 63;
    out[(long)z * sOut + (long)(c0 + c) * outStride + r0 + r] = tile[r][c];
  }
}

// per-row top-4 (descending, ties -> lower index, matching lax.top_k)
__global__ __launch_bounds__(64)
void topk_k(const float* __restrict__ sim, int* __restrict__ idx4)
{
  long row = blockIdx.x;
  const float* p = sim + row * 1024;
  int t = threadIdx.x;
  int c0 = -1, c1 = -1, c2 = -1, c3 = -1;
#pragma unroll
  for (int pass = 0; pass < 4; ++pass) {
    float best = -INFINITY;
    int bi = 1 << 30;
    for (int j = t; j < 1024; j += 64) {
      if (j == c0 || j == c1 || j == c2 || j == c3) continue;
      float v = p[j];
      if (v > best || (v == best && j < bi)) { best = v; bi = j; }
    }
#pragma unroll
    for (int off = 32; off; off >>= 1) {
      float ov = __shfl_down(best, off);
      int   oi = __shfl_down(bi, off);
      if (ov > best || (ov == best && oi < bi)) { best = ov; bi = oi; }
    }
    bi = __shfl(bi, 0);
    if (pass == 0) c0 = bi; else if (pass == 1) c1 = bi;
    else if (pass == 2) c2 = bi; else c3 = bi;
  }
  if (t == 0) { int* q = idx4 + row * 4; q[0] = c0; q[1] = c1; q[2] = c2; q[3] = c3; }
}

// adjacency -> bf16 + invcnt, from fp32 sim chunk (chunk-local rows)
__global__ __launch_bounds__(256)
void adjbf_k(const float* __restrict__ sim, const int* __restrict__ idx4,
             u16* __restrict__ adjb, float* __restrict__ invcnt)
{
  long row = blockIdx.x;
  int b = (int)(row >> 10);
  int i = (int)(row & 1023);
  const float* prow = sim + row * 1024;
  u16* arow_ = adjb + row * 1024;
  const int* my = idx4 + row * 4;
  int m0 = my[0], m1 = my[1], m2 = my[2], m3 = my[3];
  int t = threadIdx.x;
  float lsum = 0.f;
  for (int j = t; j < 1024; j += 256) {
    float v = prow[j];
    bool present = false;
    if (j != i) {
      present = (j == m0) | (j == m1) | (j == m2) | (j == m3);
      if (!present) {
        const int* oj = idx4 + (((long)b << 10) + j) * 4;
        present = (oj[0] == i) | (oj[1] == i) | (oj[2] == i) | (oj[3] == i);
      }
    }
    float a = present ? v : 0.f;
    arow_[j] = f2bf(a);
    lsum += a;
  }
  __shared__ float red[4];
  float s = wsum(lsum);
  if ((t & 63) == 0) red[t >> 6] = s;
  __syncthreads();
  if (t == 0) {
    float tot = red[0] + red[1] + red[2] + red[3];
    invcnt[row] = 1.f / fmaxf(tot, 1.f);
  }
}

// pooled_bf[128][512]: rows<32 = mean_s x2_bf, rows>=32 = 0
__global__ __launch_bounds__(256)
void poolbf_k(const u16* __restrict__ x2, u16* __restrict__ pooled)
{
  int i = blockIdx.x * 256 + threadIdx.x;   // 0..65535
  int b = i >> 9, d = i & 511;
  float s = 0.f;
  if (b < 32) {
    const u16* p = x2 + ((long)b << 10) * 512 + d;
    for (int sdx = 0; sdx < 1024; ++sdx) s += bf2f(p[(long)sdx * 512]);
    s *= (1.f / 1024.f);
  }
  pooled[i] = f2bf(s);
}

// ---------------------------------------------------------------------------
static inline void bgemm2(hipStream_t st,
    const u16* A, const u16* A2, const u16* B, const u16* B2,
    int K1, int K2, int lda, int lda2, int ldb, int ldb2,
    const float* bias, const float* resid, const u16* residH, const u16* residL,
    const float* rsc, const float* csc,
    float* Cf, u16* Cb, u16* Cb2,
    int M, int N, int ldc, long sA, long sA2, long sB, long sB2, long sC, int sS,
    float alpha, int flags, int nz, int Mstore = -1)
{
  dim3 g(M / 128, N / 128, nz);
  bgemm_k<<<g, 256, 0, st>>>(A, A2, B, B2, bias, resid, residH, residL,
                             rsc, csc, Cf, Cb, Cb2,
                             K1, K2, lda, lda2, ldb, ldb2, ldc,
                             sA, sA2, sB, sB2, sC, sS, alpha, flags,
                             Mstore < 0 ? M : Mstore);
}

static inline void bgemm(hipStream_t st, const u16* A, const u16* B,
    const float* bias, const float* resid, const u16* residH, const u16* residL,
    const float* rsc, const float* csc, float* Cf, u16* Cb, u16* Cb2,
    int M, int N, int K, int lda, int ldb, int ldc,
    long sA, long sB, long sC, int sS, float alpha, int flags, int nz,
    int Mstore = -1)
{
  bgemm2(st, A, nullptr, B, nullptr, K, 0, lda, 0, ldb, 0,
         bias, resid, residH, residL, rsc, csc, Cf, Cb, Cb2,
         M, N, ldc, sA, 0, sB, 0, sC, sS, alpha, flags, nz, Mstore);
}

extern "C" void kernel_launch(void* const* d_in, const int* in_sizes, int n_in,
                              void* d_out, int out_size, void* d_ws, size_t ws_size,
                              hipStream_t stream)
{
  (void)in_sizes; (void)n_in; (void)out_size;
  const float* x     = (const float*)d_in[0];
  const float* enc_w = (const float*)d_in[1];
  const float* enc_b = (const float*)d_in[2];
  const float* in_w  = (const float*)d_in[3];
  const float* in_b  = (const float*)d_in[4];
  const float* out_w = (const float*)d_in[5];
  const float* out_b = (const float*)d_in[6];
  const float* ln1_g = (const float*)d_in[7];
  const float* ln1_b = (const float*)d_in[8];
  const float* fw1   = (const float*)d_in[9];
  const float* fb1   = (const float*)d_in[10];
  const float* fw2   = (const float*)d_in[11];
  const float* fb2   = (const float*)d_in[12];
  const float* gc_w  = (const float*)d_in[13];
  const float* gc_b  = (const float*)d_in[14];
  const float* ln2_g = (const float*)d_in[15];
  const float* ln2_b = (const float*)d_in[16];
  const float* dec_w = (const float*)d_in[17];
  const float* dec_b = (const float*)d_in[18];
  float* out = (float*)d_out;

  // ---- arena (bytes): 3x32MB bf16 + 6.3MB weights + smalls + 84MB scratch ----
  char* base = (char*)d_ws;
  u16*  bf1  = (u16*)(base);                  // h_bf -> x1_hi (in place)
  u16*  lob  = (u16*)(base + 33554432);       // x1_lo
  u16*  bf2  = (u16*)(base + 67108864);       // ctx -> nsum -> x2
  u16*  wgt  = (u16*)(base + 100663296);      // bf16 weights
  float* invn    = (float*)(base + 106954752);
  float* invcnt  = (float*)(base + 107085824);
  u16*   pooledb = (u16*)(base + 107216896);
  int*   idx4    = (int*)(base + 107347968);
  char*  scr     = base + 107872256;          // 84MB scratch, phase-multiplexed
  const size_t need = 107872256 + 83886080;
  if (ws_size < need) return;

  u16* encw = wgt;
  u16* inw  = wgt + 262144;
  u16* outw = wgt + 1048576;
  u16* fw1b = wgt + 1310720;
  u16* fw2b = wgt + 1835008;
  u16* gcwb = wgt + 2359296;
  u16* decw = wgt + 2883584;

  const int Mtok = 32768;

  // ---- casts ----
  u16* xbf = (u16*)scr;
  castbf_k<<<65536, 256, 0, stream>>>(x, xbf, 16777216);
  castbf_k<<<1024, 256, 0, stream>>>(enc_w, encw, 262144);
  castbf_k<<<3072, 256, 0, stream>>>(in_w,  inw,  786432);
  castbf_k<<<1024, 256, 0, stream>>>(out_w, outw, 262144);
  castbf_k<<<2048, 256, 0, stream>>>(fw1,   fw1b, 524288);
  castbf_k<<<2048, 256, 0, stream>>>(fw2,   fw2b, 524288);
  castbf_k<<<2048, 256, 0, stream>>>(gc_w,  gcwb, 524288);
  castbf_k<<<1024, 256, 0, stream>>>(dec_w, decw, 262144);

  // 1. h_bf = relu(x @ enc_w^T + enc_b)
  bgemm(stream, xbf, encw, enc_b, nullptr, nullptr, nullptr, nullptr, nullptr,
        nullptr, bf1, nullptr, Mtok, 512, 512, 512, 512, 512, 0, 0, 0, 0,
        1.f, F_RELU, 1);

  // 2+3. attention: 4 chunks x 8 batches
  for (int c = 0; c < 4; ++c) {
    long row0 = (long)c * 8192;
    u16*   qkvc = (u16*)scr;                        // 8192x1536 u16 (24MB)
    float* scc  = (float*)(scr + 25165824);         // [8][2][1024][1024] f32 (was per-head? no: [8 batches][2 heads])
    u16*   Pus  = (u16*)(scr + 25165824 + 33554432 - 33554432 + 33554432); // placeholder
    // layout: qkvc 24MB | scc 32MB? -> need [8][2][1024][1024] = 64MB; too big.
    // Instead: per-head scores (32MB): scc = [8][1024][1024] f32 for one head.
    (void)Pus;
    bgemm(stream, bf1 + row0 * 512, inw, in_b, nullptr, nullptr, nullptr,
          nullptr, nullptr, nullptr, qkvc, nullptr,
          8192, 1536, 512, 512, 512, 1536, 0, 0, 0, 0, 1.f, 0, 1);
    float* sch = (float*)(scr + 25165824);          // 32MB: one head, 8 batches
    u16*   Ph  = (u16*)(scr + 25165824 + 33554432); // 16MB
    u16*   vT  = (u16*)(scr + 25165824 + 33554432 + 16777216); // 4MB
    for (int h = 0; h < 2; ++h) {
      bgemm(stream, qkvc + h * 256, qkvc + 512 + h * 256, nullptr, nullptr,
            nullptr, nullptr, nullptr, nullptr, sch, nullptr, nullptr,
            1024, 1024, 256, 1536, 1536, 1024,
            1572864, 1572864, 1048576, 0, 0.0625f, 0, 8);
      softmaxbf_k<<<8192, 256, 0, stream>>>(sch, Ph);
      transp_k<<<dim3(16, 4, 8), 256, 0, stream>>>(
          qkvc + 1024 + h * 256, vT, 1536, 1024, 1572864, 262144);
      bgemm(stream, Ph, vT, nullptr, nullptr, nullptr, nullptr, nullptr,
            nullptr, nullptr, bf2 + row0 * 512 + h * 256, nullptr,
            1024, 256, 1024, 1024, 1024, 512,
            1048576, 262144, 524288, 0, 1.f, 0, 8);
    }
  }

  // 4. attn_out (fp32, full)
  float* aoc = (float*)scr;                         // 64MB
  bgemm(stream, bf2, outw, out_b, nullptr, nullptr, nullptr, nullptr, nullptr,
        aoc, nullptr, nullptr, Mtok, 512, 512, 512, 512, 512, 0, 0, 0, 0,
        1.f, 0, 1);

  // 5. x1 = LN(h + attn_out) -> hi (in place) + lo
  ln1_k<<<Mtok, 256, 0, stream>>>(bf1, aoc, ln1_g, ln1_b, bf1, lob);

  // 6+7. FFN (full)
  u16* mid = (u16*)scr;                             // 64MB
  bgemm(stream, bf1, fw1b, fb1, nullptr, nullptr, nullptr, nullptr, nullptr,
        nullptr, mid, nullptr, Mtok, 1024, 512, 512, 512, 1024, 0, 0, 0, 0,
        1.f, F_RELU, 1);
  bgemm(stream, mid, fw2b, fb2, nullptr, bf1, lob, nullptr, nullptr,
        nullptr, bf1, lob, Mtok, 512, 1024, 1024, 1024, 512, 0, 0, 0, 0,
        1.f, F_RESID2, 1);

  // 8. row norms (hi+lo)
  rownorm_k<<<Mtok, 256, 0, stream>>>(bf1, lob, invn);

  // 9-12. graph: 4 chunks x 8 batches
  for (int g = 0; g < 4; ++g) {
    long row0 = (long)g * 8192;
    float* simc = (float*)scr;                      // 32MB
    u16*   adjb = (u16*)(scr + 33554432);           // 16MB
    u16*   x1T  = (u16*)(scr + 33554432 + 16777216);// 8MB
    // sim = hi.hi^T  (K=512), then += hi.lo^T + lo.hi^T (dual-seg K=1024), scale
    bgemm(stream, bf1 + row0 * 512, bf1 + row0 * 512, nullptr, nullptr,
          nullptr, nullptr, nullptr, nullptr, simc, nullptr, nullptr,
          1024, 1024, 512, 512, 512, 1024, 524288, 524288, 1048576, 0,
          1.f, 0, 8);
    bgemm2(stream, bf1 + row0 * 512, lob + row0 * 512,
           lob + row0 * 512, bf1 + row0 * 512,
           512, 512, 512, 512, 512, 512,
           nullptr, nullptr, nullptr, nullptr, invn + row0, invn + row0,
           simc, nullptr, nullptr, 1024, 1024, 1024,
           524288, 524288, 524288, 524288, 1048576, 1024,
           1.f, F_ACC | F_SIMSC, 8);
    topk_k<<<8192, 64, 0, stream>>>(simc, idx4 + row0 * 4);
    adjbf_k<<<8192, 256, 0, stream>>>(simc, idx4 + row0 * 4, adjb, invcnt + row0);
    transp_k<<<dim3(16, 8, 8), 256, 0, stream>>>(bf1 + row0 * 512, x1T,
                                                 512, 1024, 524288, 524288);
    bgemm(stream, adjb, x1T, nullptr, nullptr, nullptr, nullptr,
          invcnt + row0, nullptr, nullptr, bf2 + row0 * 512, nullptr,
          1024, 512, 1024, 1024, 1024, 512, 1048576, 524288, 524288, 1024,
          1.f, F_ROWSC, 8);
  }

  // 13/14. gcout = x1_hi @ gcW1^T + nsum @ gcW2^T + gc_b   (one dual-seg GEMM)
  float* gch = (float*)scr;                         // 64MB
  bgemm2(stream, bf1, bf2, gcwb, gcwb + 512,
         512, 512, 512, 512, 1024, 1024,
         gc_b, nullptr, nullptr, nullptr, nullptr, nullptr,
         gch, nullptr, nullptr, Mtok, 512, 512, 0, 0, 0, 0, 0, 0,
         1.f, 0, 1);

  // 15. x2 = LN(x1 + gcout) -> bf16 (over bf2; nsum consumed)
  ln2_k<<<Mtok, 256, 0, stream>>>(bf1, lob, gch, ln2_g, ln2_b, bf2);

  // 16+17. pool + decoder
  poolbf_k<<<256, 256, 0, stream>>>(bf2, pooledb);
  bgemm(stream, pooledb, decw, dec_b, nullptr, nullptr, nullptr, nullptr,
        nullptr, out, nullptr, nullptr, 128, 512, 512, 512, 512, 512,
        0, 0, 0, 0, 1.f, 0, 1, 32);
}

// Round 5
// 1612.477 us; speedup vs baseline: 5.3569x; 1.2683x over previous
//
#include <hip/hip_runtime.h>
#include <hip/hip_bf16.h>
#include <math.h>

typedef unsigned short u16;
typedef __attribute__((ext_vector_type(8))) short bfrag;   // 8 bf16 (4 VGPR)
typedef __attribute__((ext_vector_type(4))) float facc;    // 4 fp32 acc
typedef const __attribute__((address_space(1))) void* gaddr_t;
typedef __attribute__((address_space(3))) void* laddr_t;

#define F_RELU   1
#define F_ROWSC  4   // *= rsc[m]
#define F_SIMSC  8   // *= rsc[m]*csc[n]
#define F_RESID2 32  // += bf16 residH + residL

__device__ __forceinline__ u16 f2bf(float f) {
  __hip_bfloat16 h = __float2bfloat16(f);
  return *reinterpret_cast<u16*>(&h);
}
__device__ __forceinline__ float bf2f(u16 u) {
  __hip_bfloat16 h = *reinterpret_cast<__hip_bfloat16*>(&u);
  return __bfloat162float(h);
}
__device__ __forceinline__ float wsum(float v) {
#pragma unroll
  for (int o = 32; o; o >>= 1) v += __shfl_xor(v, o);
  return v;
}
__device__ __forceinline__ float wmaxf(float v) {
#pragma unroll
  for (int o = 32; o; o >>= 1) v = fmaxf(v, __shfl_xor(v, o));
  return v;
}

struct GSeg {
  const u16* A; const u16* B;
  long sA, sB;          // per-z strides
  int lda, ldb, K;      // K % 64 == 0
  int hA, hB;           // per-head offsets (headBits mode)
};

// ---------------------------------------------------------------------------
// bf16 MFMA GEMM, up to 3 K-segments: C = epi(alpha * sum_s A_s @ B_s^T)
// 256 thr = 4 waves; tile 128x128; BK=64; wave = 64x64 (4x4 of 16x16x32).
// LDS row stride 64 elems (=128B = all 32 banks); slot g' = g ^ ((row>>1)&7)
// -> ds_read_b128 conflict-free (2-way max, free).
// headBits: blockIdx.z = zb*2 + h; per-head offsets hA/hB/hC.
// ---------------------------------------------------------------------------
__global__ __launch_bounds__(256)
void bgemm_k(GSeg s0, GSeg s1, GSeg s2, int nseg,
             const float* __restrict__ bias,
             const u16* __restrict__ residH, const u16* __restrict__ residL,
             const float* __restrict__ rsc, const float* __restrict__ csc,
             float* __restrict__ Cf, u16* __restrict__ Cb, u16* __restrict__ Cb2,
             int ldc, long sC, int hC, int headBits, int sS,
             float alpha, int flags, int Mstore)
{
  const int zAll = blockIdx.z;
  const int hIdx = headBits ? (zAll & 1) : 0;
  const int z    = headBits ? (zAll >> 1) : zAll;
  const long cofs = (long)z * sC + (long)hIdx * hC;
  const float* rs = rsc ? rsc + (long)z * sS : nullptr;
  const float* cs = csc ? csc + (long)z * sS : nullptr;

  __shared__ u16 As[128 * 64];
  __shared__ u16 Bs[128 * 64];

  const int tid  = threadIdx.x;
  const int wave = tid >> 6, lane = tid & 63;
  const int m0 = blockIdx.x * 128, n0 = blockIdx.y * 128;
  const int wrow = (wave >> 1) * 64, wcol = (wave & 1) * 64;

  // staging: wave stages rows [wave*32, wave*32+32) of A and B.
  // one glds inst = 8 rows x 8 groups (64 lanes x 16B = 1KB).
  const int lrow = lane >> 3;          // 0..7
  const int lgrp = lane & 7;           // 0..7

  facc acc[4][4];
#pragma unroll
  for (int i = 0; i < 4; ++i)
#pragma unroll
    for (int j = 0; j < 4; ++j) acc[i][j] = (facc)(0.f);

  const int r16 = lane & 15, gq = lane >> 4;

  for (int seg = 0; seg < nseg; ++seg) {
    const GSeg& S = seg == 0 ? s0 : (seg == 1 ? s1 : s2);
    const u16* Ab = S.A + (long)z * S.sA + (long)hIdx * S.hA;
    const u16* Bb = S.B + (long)z * S.sB + (long)hIdx * S.hB;
    for (int k0 = 0; k0 < S.K; k0 += 64) {
#pragma unroll
      for (int ss = 0; ss < 4; ++ss) {
        int rloc = wave * 32 + ss * 8;
        int row  = rloc + lrow;
        int g    = lgrp ^ ((row >> 1) & 7);
        __builtin_amdgcn_global_load_lds(
            (gaddr_t)(const void*)(Ab + (long)(m0 + row) * S.lda + k0 + g * 8),
            (laddr_t)(As + rloc * 64), 16, 0, 0);
        __builtin_amdgcn_global_load_lds(
            (gaddr_t)(const void*)(Bb + (long)(n0 + row) * S.ldb + k0 + g * 8),
            (laddr_t)(Bs + rloc * 64), 16, 0, 0);
      }
      __syncthreads();

#pragma unroll
      for (int kk = 0; kk < 2; ++kk) {
        bfrag af[4], bb[4];
#pragma unroll
        for (int mt = 0; mt < 4; ++mt) {
          int r = wrow + mt * 16 + r16;
          int slot = (kk * 4 + gq) ^ ((r >> 1) & 7);
          af[mt] = *(const bfrag*)&As[r * 64 + slot * 8];
        }
#pragma unroll
        for (int nt = 0; nt < 4; ++nt) {
          int r = wcol + nt * 16 + r16;
          int slot = (kk * 4 + gq) ^ ((r >> 1) & 7);
          bb[nt] = *(const bfrag*)&Bs[r * 64 + slot * 8];
        }
#pragma unroll
        for (int mt = 0; mt < 4; ++mt)
#pragma unroll
          for (int nt = 0; nt < 4; ++nt)
            acc[mt][nt] = __builtin_amdgcn_mfma_f32_16x16x32_bf16(
                af[mt], bb[nt], acc[mt][nt], 0, 0, 0);
      }
      __syncthreads();
    }
  }

  // epilogue: C/D layout col = lane&15, row = (lane>>4)*4 + reg
#pragma unroll
  for (int mt = 0; mt < 4; ++mt) {
#pragma unroll
    for (int nt = 0; nt < 4; ++nt) {
#pragma unroll
      for (int r = 0; r < 4; ++r) {
        int gm = m0 + wrow + mt * 16 + gq * 4 + r;
        int gn = n0 + wcol + nt * 16 + r16;
        if (gm >= Mstore) continue;
        float v = acc[mt][nt][r] * alpha;
        long ci = cofs + (long)gm * ldc + gn;
        if (flags & F_SIMSC)  v *= rs[gm] * cs[gn];
        if (flags & F_ROWSC)  v *= rs[gm];
        if (bias)             v += bias[gn];
        if (flags & F_RESID2) v += bf2f(residH[ci]) + bf2f(residL[ci]);
        if (flags & F_RELU)   v = fmaxf(v, 0.f);
        if (Cf) Cf[ci] = v;
        if (Cb) {
          u16 hv = f2bf(v);
          Cb[ci] = hv;
          if (Cb2) Cb2[ci] = f2bf(v - bf2f(hv));
        }
      }
    }
  }
}

// ---------------------------------------------------------------------------
__global__ __launch_bounds__(256)
void castbf_k(const float* __restrict__ in, u16* __restrict__ out, int n)
{
  int i = blockIdx.x * 256 + threadIdx.x;
  if (i < n) out[i] = f2bf(in[i]);
}

// all 7 weight matrices in one launch (layout matches wgt arena)
__global__ __launch_bounds__(256)
void castw_k(const float* w0, const float* w1, const float* w2,
             const float* w3, const float* w4, const float* w5,
             const float* w6, u16* __restrict__ dst)
{
  int i = blockIdx.x * 256 + threadIdx.x;
  const float* s; int off;
  if      (i < 262144)  { s = w0; off = 0; }
  else if (i < 1048576) { s = w1; off = 262144; }
  else if (i < 1310720) { s = w2; off = 1048576; }
  else if (i < 1835008) { s = w3; off = 1310720; }
  else if (i < 2359296) { s = w4; off = 1835008; }
  else if (i < 2883584) { s = w5; off = 2359296; }
  else                  { s = w6; off = 2883584; }
  dst[i] = f2bf(s[i - off]);
}

// x1 = LN(bf16 a + bf16 b) -> hi (in place over a ok) + lo
__global__ __launch_bounds__(256)
void ln1_k(const u16* __restrict__ a, const u16* __restrict__ b,
           const float* __restrict__ g, const float* __restrict__ be,
           u16* __restrict__ oh, u16* __restrict__ ol)
{
  long base = (long)blockIdx.x * 512;
  int t = threadIdx.x;
  float v0 = bf2f(a[base + t])       + bf2f(b[base + t]);
  float v1 = bf2f(a[base + t + 256]) + bf2f(b[base + t + 256]);
  __shared__ float red[4], red2[4];
  float s = wsum(v0 + v1);
  if ((t & 63) == 0) red[t >> 6] = s;
  __syncthreads();
  float mean = (red[0] + red[1] + red[2] + red[3]) * (1.f / 512.f);
  float c0 = v0 - mean, c1 = v1 - mean;
  float ss = wsum(c0 * c0 + c1 * c1);
  if ((t & 63) == 0) red2[t >> 6] = ss;
  __syncthreads();
  float var = (red2[0] + red2[1] + red2[2] + red2[3]) * (1.f / 512.f);
  float rstd = rsqrtf(var + 1e-5f);
  float o0 = c0 * rstd * g[t]       + be[t];
  float o1 = c1 * rstd * g[t + 256] + be[t + 256];
  u16 h0 = f2bf(o0), h1 = f2bf(o1);
  oh[base + t] = h0;       oh[base + t + 256] = h1;
  ol[base + t] = f2bf(o0 - bf2f(h0));
  ol[base + t + 256] = f2bf(o1 - bf2f(h1));
}

// x2 = LN((hi+lo) + bf16 b) -> bf16
__global__ __launch_bounds__(256)
void ln2_k(const u16* __restrict__ hi, const u16* __restrict__ lo,
           const u16* __restrict__ b, const float* __restrict__ g,
           const float* __restrict__ be, u16* __restrict__ ob)
{
  long base = (long)blockIdx.x * 512;
  int t = threadIdx.x;
  float v0 = bf2f(hi[base + t])       + bf2f(lo[base + t])       + bf2f(b[base + t]);
  float v1 = bf2f(hi[base + t + 256]) + bf2f(lo[base + t + 256]) + bf2f(b[base + t + 256]);
  __shared__ float red[4], red2[4];
  float s = wsum(v0 + v1);
  if ((t & 63) == 0) red[t >> 6] = s;
  __syncthreads();
  float mean = (red[0] + red[1] + red[2] + red[3]) * (1.f / 512.f);
  float c0 = v0 - mean, c1 = v1 - mean;
  float ss = wsum(c0 * c0 + c1 * c1);
  if ((t & 63) == 0) red2[t >> 6] = ss;
  __syncthreads();
  float var = (red2[0] + red2[1] + red2[2] + red2[3]) * (1.f / 512.f);
  float rstd = rsqrtf(var + 1e-5f);
  ob[base + t]       = f2bf(c0 * rstd * g[t]       + be[t]);
  ob[base + t + 256] = f2bf(c1 * rstd * g[t + 256] + be[t + 256]);
}

// invn[row] = 1/max(||hi+lo||, 1e-12)
__global__ __launch_bounds__(256)
void rownorm_k(const u16* __restrict__ hi, const u16* __restrict__ lo,
               float* __restrict__ invn)
{
  long base = (long)blockIdx.x * 512;
  int t = threadIdx.x;
  float v0 = bf2f(hi[base + t])       + bf2f(lo[base + t]);
  float v1 = bf2f(hi[base + t + 256]) + bf2f(lo[base + t + 256]);
  __shared__ float red[4];
  float s = wsum(v0 * v0 + v1 * v1);
  if ((t & 63) == 0) red[t >> 6] = s;
  __syncthreads();
  if (t == 0) {
    float tot = red[0] + red[1] + red[2] + red[3];
    invn[blockIdx.x] = 1.f / fmaxf(sqrtf(tot), 1e-12f);
  }
}

// in-place row softmax over 1024 bf16
__global__ __launch_bounds__(256)
void softmaxu_k(u16* __restrict__ sc)
{
  long row = blockIdx.x;
  u16* p = sc + row * 1024;
  int t = threadIdx.x;
  float v[4];
#pragma unroll
  for (int i = 0; i < 4; ++i) v[i] = bf2f(p[t + 256 * i]);
  __shared__ float redm[4], redsum[4];
  float m4 = fmaxf(fmaxf(v[0], v[1]), fmaxf(v[2], v[3]));
  float wm = wmaxf(m4);
  if ((t & 63) == 0) redm[t >> 6] = wm;
  __syncthreads();
  float MX = fmaxf(fmaxf(redm[0], redm[1]), fmaxf(redm[2], redm[3]));
  float s = 0.f;
#pragma unroll
  for (int i = 0; i < 4; ++i) { v[i] = __expf(v[i] - MX); s += v[i]; }
  float ws_ = wsum(s);
  if ((t & 63) == 0) redsum[t >> 6] = ws_;
  __syncthreads();
  float inv = 1.f / (redsum[0] + redsum[1] + redsum[2] + redsum[3]);
#pragma unroll
  for (int i = 0; i < 4; ++i) p[t + 256 * i] = f2bf(v[i] * inv);
}

// 64x64 tiled u16 transpose; z = zb*2+h when headBits
__global__ __launch_bounds__(256)
void transp_k(const u16* __restrict__ in, u16* __restrict__ out,
              int inStride, int outStride, long sIn, long sOut,
              int hIn, int headBits)
{
  const int zAll = blockIdx.z;
  const int h  = headBits ? (zAll & 1) : 0;
  const int zb = headBits ? (zAll >> 1) : zAll;
  const u16* src = in + (long)zb * sIn + (long)h * hIn;
  u16* dst = out + (long)zAll * sOut;
  const int r0 = blockIdx.x * 64, c0 = blockIdx.y * 64;
  __shared__ u16 tile[64][66];
  const int t = threadIdx.x;
#pragma unroll
  for (int p = 0; p < 16; ++p) {
    int idx = p * 256 + t;
    int r = idx >> 6, c = idx & 63;
    tile[r][c] = src[(long)(r0 + r) * inStride + c0 + c];
  }
  __syncthreads();
#pragma unroll
  for (int p = 0; p < 16; ++p) {
    int idx = p * 256 + t;
    int c = idx >> 6, r = idx & 63;
    dst[(long)(c0 + c) * outStride + r0 + r] = tile[r][c];
  }
}

// per-row top-4 (descending, ties -> lower index, matching lax.top_k)
__global__ __launch_bounds__(64)
void topk_k(const float* __restrict__ sim, int* __restrict__ idx4)
{
  long row = blockIdx.x;
  const float* p = sim + row * 1024;
  int t = threadIdx.x;
  int c0 = -1, c1 = -1, c2 = -1, c3 = -1;
#pragma unroll
  for (int pass = 0; pass < 4; ++pass) {
    float best = -INFINITY;
    int bi = 1 << 30;
    for (int j = t; j < 1024; j += 64) {
      if (j == c0 || j == c1 || j == c2 || j == c3) continue;
      float v = p[j];
      if (v > best || (v == best && j < bi)) { best = v; bi = j; }
    }
#pragma unroll
    for (int off = 32; off; off >>= 1) {
      float ov = __shfl_down(best, off);
      int   oi = __shfl_down(bi, off);
      if (ov > best || (ov == best && oi < bi)) { best = ov; bi = oi; }
    }
    bi = __shfl(bi, 0);
    if (pass == 0) c0 = bi; else if (pass == 1) c1 = bi;
    else if (pass == 2) c2 = bi; else c3 = bi;
  }
  if (t == 0) { int* q = idx4 + row * 4; q[0] = c0; q[1] = c1; q[2] = c2; q[3] = c3; }
}

// adjacency -> bf16 + invcnt, from fp32 sim chunk (chunk-local rows)
__global__ __launch_bounds__(256)
void adjbf_k(const float* __restrict__ sim, const int* __restrict__ idx4,
             u16* __restrict__ adjb, float* __restrict__ invcnt)
{
  long row = blockIdx.x;
  int b = (int)(row >> 10);
  int i = (int)(row & 1023);
  const float* prow = sim + row * 1024;
  u16* arow_ = adjb + row * 1024;
  const int* my = idx4 + row * 4;
  int m0 = my[0], m1 = my[1], m2 = my[2], m3 = my[3];
  int t = threadIdx.x;
  float lsum = 0.f;
  for (int j = t; j < 1024; j += 256) {
    float v = prow[j];
    bool present = false;
    if (j != i) {
      present = (j == m0) | (j == m1) | (j == m2) | (j == m3);
      if (!present) {
        const int* oj = idx4 + (((long)b << 10) + j) * 4;
        present = (oj[0] == i) | (oj[1] == i) | (oj[2] == i) | (oj[3] == i);
      }
    }
    float a = present ? v : 0.f;
    arow_[j] = f2bf(a);
    lsum += a;
  }
  __shared__ float red[4];
  float s = wsum(lsum);
  if ((t & 63) == 0) red[t >> 6] = s;
  __syncthreads();
  if (t == 0) {
    float tot = red[0] + red[1] + red[2] + red[3];
    invcnt[row] = 1.f / fmaxf(tot, 1.f);
  }
}

// pooled_bf[128][512]: rows<32 = mean_s x2_bf, rows>=32 = 0
__global__ __launch_bounds__(256)
void poolbf_k(const u16* __restrict__ x2, u16* __restrict__ pooled)
{
  int i = blockIdx.x * 256 + threadIdx.x;   // 0..65535
  int b = i >> 9, d = i & 511;
  float s = 0.f;
  if (b < 32) {
    const u16* p = x2 + ((long)b << 10) * 512 + d;
    for (int sdx = 0; sdx < 1024; ++sdx) s += bf2f(p[(long)sdx * 512]);
    s *= (1.f / 1024.f);
  }
  pooled[i] = f2bf(s);
}

// ---------------------------------------------------------------------------
static inline GSeg mkseg(const u16* A, const u16* B, int K, int lda, int ldb,
                         long sA = 0, long sB = 0, int hA = 0, int hB = 0)
{
  GSeg s; s.A = A; s.B = B; s.K = K; s.lda = lda; s.ldb = ldb;
  s.sA = sA; s.sB = sB; s.hA = hA; s.hB = hB; return s;
}

static inline void bgemm(hipStream_t st, GSeg s0, GSeg s1, GSeg s2, int nseg,
    const float* bias, const u16* residH, const u16* residL,
    const float* rsc, const float* csc, float* Cf, u16* Cb, u16* Cb2,
    int M, int N, int ldc, long sC, int hC, int headBits, int sS,
    float alpha, int flags, int nz, int Mstore = -1)
{
  dim3 g(M / 128, N / 128, nz);
  bgemm_k<<<g, 256, 0, st>>>(s0, s1, s2, nseg, bias, residH, residL,
                             rsc, csc, Cf, Cb, Cb2, ldc, sC, hC, headBits,
                             sS, alpha, flags, Mstore < 0 ? M : Mstore);
}

extern "C" void kernel_launch(void* const* d_in, const int* in_sizes, int n_in,
                              void* d_out, int out_size, void* d_ws, size_t ws_size,
                              hipStream_t stream)
{
  (void)in_sizes; (void)n_in; (void)out_size;
  const float* x     = (const float*)d_in[0];
  const float* enc_w = (const float*)d_in[1];
  const float* enc_b = (const float*)d_in[2];
  const float* in_w  = (const float*)d_in[3];
  const float* in_b  = (const float*)d_in[4];
  const float* out_w = (const float*)d_in[5];
  const float* out_b = (const float*)d_in[6];
  const float* ln1_g = (const float*)d_in[7];
  const float* ln1_b = (const float*)d_in[8];
  const float* fw1   = (const float*)d_in[9];
  const float* fb1   = (const float*)d_in[10];
  const float* fw2   = (const float*)d_in[11];
  const float* fb2   = (const float*)d_in[12];
  const float* gc_w  = (const float*)d_in[13];
  const float* gc_b  = (const float*)d_in[14];
  const float* ln2_g = (const float*)d_in[15];
  const float* ln2_b = (const float*)d_in[16];
  const float* dec_w = (const float*)d_in[17];
  const float* dec_b = (const float*)d_in[18];
  float* out = (float*)d_out;

  // ---- arena ----
  char* base = (char*)d_ws;
  u16*  bf1  = (u16*)(base);                  // h_bf -> x1_hi (in place)
  u16*  lob  = (u16*)(base + 33554432);       // x1_lo
  u16*  bf2  = (u16*)(base + 67108864);       // ctx -> nsum -> x2
  u16*  wgt  = (u16*)(base + 100663296);      // bf16 weights
  float* invn    = (float*)(base + 106954752);
  float* invcnt  = (float*)(base + 107085824);
  u16*   pooledb = (u16*)(base + 107216896);
  int*   idx4    = (int*)(base + 107347968);
  char*  scr     = base + 107872256;          // 80MB scratch, phase-multiplexed
  const size_t need = 107872256 + 83886080;
  if (ws_size < need) return;

  u16* encw = wgt;
  u16* inw  = wgt + 262144;
  u16* outw = wgt + 1048576;
  u16* fw1b = wgt + 1310720;
  u16* fw2b = wgt + 1835008;
  u16* gcwb = wgt + 2359296;
  u16* decw = wgt + 2883584;

  const int Mtok = 32768;
  GSeg Z = mkseg(nullptr, nullptr, 0, 0, 0);

  // ---- casts ----
  u16* xbf = (u16*)scr;
  castbf_k<<<65536, 256, 0, stream>>>(x, xbf, 16777216);
  castw_k<<<12288, 256, 0, stream>>>(enc_w, in_w, out_w, fw1, fw2, gc_w, dec_w, wgt);

  // 1. h_bf = relu(x @ enc_w^T + enc_b)
  bgemm(stream, mkseg(xbf, encw, 512, 512, 512), Z, Z, 1,
        enc_b, nullptr, nullptr, nullptr, nullptr, nullptr, bf1, nullptr,
        Mtok, 512, 512, 0, 0, 0, 0, 1.f, F_RELU, 1);

  // 2+3. attention: 4 chunks x 8 batches, heads folded into z (z=16)
  for (int c = 0; c < 4; ++c) {
    long row0 = (long)c * 8192;
    u16* qkvc = (u16*)scr;                        // 8192x1536 u16 (24MB)
    u16* sco  = (u16*)(scr + 25165824);           // 16 x 1024x1024 u16 (32MB)
    u16* vT   = (u16*)(scr + 58720256);           // 16 x 256x1024 u16 (8MB)
    bgemm(stream, mkseg(bf1 + row0 * 512, inw, 512, 512, 512), Z, Z, 1,
          in_b, nullptr, nullptr, nullptr, nullptr, nullptr, qkvc, nullptr,
          8192, 1536, 1536, 0, 0, 0, 0, 1.f, 0, 1);
    // scores[z=16] = 1/16 * Q @ K^T  -> bf16
    bgemm(stream, mkseg(qkvc, qkvc + 512, 256, 1536, 1536,
                        1572864, 1572864, 256, 256), Z, Z, 1,
          nullptr, nullptr, nullptr, nullptr, nullptr, nullptr, sco, nullptr,
          1024, 1024, 1024, 2097152, 1048576, 1, 0, 0.0625f, 0, 16);
    softmaxu_k<<<16384, 256, 0, stream>>>(sco);
    transp_k<<<dim3(16, 4, 16), 256, 0, stream>>>(
        qkvc + 1024, vT, 1536, 1024, 1572864, 262144, 256, 1);
    // ctx = P @ V  (B = V^T rows = d, cols = s)
    bgemm(stream, mkseg(sco, vT, 1024, 1024, 1024,
                        2097152, 524288, 1048576, 262144), Z, Z, 1,
          nullptr, nullptr, nullptr, nullptr, nullptr, nullptr,
          bf2 + row0 * 512, nullptr,
          1024, 256, 512, 524288, 256, 1, 0, 1.f, 0, 16);
  }

  // 4. attn_out -> bf16
  u16* aoc = (u16*)scr;                           // 32MB
  bgemm(stream, mkseg(bf2, outw, 512, 512, 512), Z, Z, 1,
        out_b, nullptr, nullptr, nullptr, nullptr, nullptr, aoc, nullptr,
        Mtok, 512, 512, 0, 0, 0, 0, 1.f, 0, 1);

  // 5. x1 = LN(h + attn_out) -> hi (in place) + lo
  ln1_k<<<Mtok, 256, 0, stream>>>(bf1, aoc, ln1_g, ln1_b, bf1, lob);

  // 6+7. FFN
  u16* mid = (u16*)scr;                           // 64MB
  bgemm(stream, mkseg(bf1, fw1b, 512, 512, 512), Z, Z, 1,
        fb1, nullptr, nullptr, nullptr, nullptr, nullptr, mid, nullptr,
        Mtok, 1024, 1024, 0, 0, 0, 0, 1.f, F_RELU, 1);
  bgemm(stream, mkseg(mid, fw2b, 1024, 1024, 1024), Z, Z, 1,
        fb2, bf1, lob, nullptr, nullptr, nullptr, bf1, lob,
        Mtok, 512, 512, 0, 0, 0, 0, 1.f, F_RESID2, 1);

  // 8. row norms
  rownorm_k<<<Mtok, 256, 0, stream>>>(bf1, lob, invn);

  // 9-12. graph: x1T once, then 4 chunks x 8 batches
  float* simc = (float*)scr;                      // 32MB
  u16*   adjb = (u16*)(scr + 33554432);           // 16MB
  u16*   x1T  = (u16*)(scr + 50331648);           // 32MB (all 32 batches)
  transp_k<<<dim3(16, 8, 32), 256, 0, stream>>>(bf1, x1T, 512, 1024,
                                                524288, 524288, 0, 0);
  for (int g = 0; g < 4; ++g) {
    long row0 = (long)g * 8192;
    // sim = (hi.hi + hi.lo + lo.hi) * invn_i * invn_j   (one 3-seg GEMM)
    bgemm(stream,
          mkseg(bf1 + row0 * 512, bf1 + row0 * 512, 512, 512, 512, 524288, 524288),
          mkseg(bf1 + row0 * 512, lob + row0 * 512, 512, 512, 512, 524288, 524288),
          mkseg(lob + row0 * 512, bf1 + row0 * 512, 512, 512, 512, 524288, 524288),
          3, nullptr, nullptr, nullptr, invn + row0, invn + row0,
          simc, nullptr, nullptr,
          1024, 1024, 1024, 1048576, 0, 0, 1024, 1.f, F_SIMSC, 8);
    topk_k<<<8192, 64, 0, stream>>>(simc, idx4 + row0 * 4);
    adjbf_k<<<8192, 256, 0, stream>>>(simc, idx4 + row0 * 4, adjb, invcnt + row0);
    // nsum = (adj @ x1) * invcnt
    bgemm(stream, mkseg(adjb, x1T + row0 * 512, 1024, 1024, 1024,
                        1048576, 524288), Z, Z, 1,
          nullptr, nullptr, nullptr, invcnt + row0, nullptr, nullptr,
          bf2 + row0 * 512, nullptr,
          1024, 512, 512, 524288, 0, 0, 1024, 1.f, F_ROWSC, 8);
  }

  // 13/14. gcout = x1_hi @ gcW1^T + nsum @ gcW2^T + gc_b  (2-seg) -> bf16
  u16* gch = (u16*)scr;                           // 32MB
  bgemm(stream, mkseg(bf1, gcwb, 512, 512, 1024),
        mkseg(bf2, gcwb + 512, 512, 512, 1024), Z, 2,
        gc_b, nullptr, nullptr, nullptr, nullptr, nullptr, gch, nullptr,
        Mtok, 512, 512, 0, 0, 0, 0, 1.f, 0, 1);

  // 15. x2 = LN(x1 + gcout) -> bf16 (over bf2; nsum consumed)
  ln2_k<<<Mtok, 256, 0, stream>>>(bf1, lob, gch, ln2_g, ln2_b, bf2);

  // 16+17. pool + decoder
  poolbf_k<<<256, 256, 0, stream>>>(bf2, pooledb);
  bgemm(stream, mkseg(pooledb, decw, 512, 512, 512), Z, Z, 1,
        dec_b, nullptr, nullptr, nullptr, nullptr, out, nullptr, nullptr,
        128, 512, 512, 0, 0, 0, 0, 1.f, 0, 1, 32);
}

// Round 6
// 1605.224 us; speedup vs baseline: 5.3811x; 1.0045x over previous
//
#include <hip/hip_runtime.h>
#include <hip/hip_bf16.h>
#include <math.h>

typedef unsigned short u16;
typedef __attribute__((ext_vector_type(8))) short bfrag;   // 8 bf16 (4 VGPR)
typedef __attribute__((ext_vector_type(4))) float facc;    // 4 fp32 acc
typedef const __attribute__((address_space(1))) void* gaddr_t;
typedef __attribute__((address_space(3))) void* laddr_t;

#define F_RELU   1
#define F_ROWSC  4   // *= rsc[m]
#define F_SIMSC  8   // *= rsc[m]*csc[n]
#define F_RESID2 32  // += bf16 residH + residL

__device__ __forceinline__ u16 f2bf(float f) {
  __hip_bfloat16 h = __float2bfloat16(f);
  return *reinterpret_cast<u16*>(&h);
}
__device__ __forceinline__ float bf2f(u16 u) {
  __hip_bfloat16 h = *reinterpret_cast<__hip_bfloat16*>(&u);
  return __bfloat162float(h);
}
__device__ __forceinline__ float wsum(float v) {
#pragma unroll
  for (int o = 32; o; o >>= 1) v += __shfl_xor(v, o);
  return v;
}
__device__ __forceinline__ float wmaxf(float v) {
#pragma unroll
  for (int o = 32; o; o >>= 1) v = fmaxf(v, __shfl_xor(v, o));
  return v;
}

struct GSeg {
  const u16* A; const u16* B;
  long sA, sB;          // per-z strides
  int lda, ldb, K;      // K % 64 == 0
  int hA, hB;           // per-head offsets (headBits mode)
};

// ---------------------------------------------------------------------------
// bf16 MFMA GEMM, up to 3 K-segments: C = epi(alpha * sum_s A_s @ B_s^T)
// 256 thr = 4 waves; tile 128x128; BK=64; wave = 64x64 (4x4 of 16x16x32).
// DOUBLE-BUFFERED LDS (2 x 32KB): stage iter k+1 while MFMA on iter k, one
// barrier per iter drains a glds round that had a full MFMA phase in flight.
// LDS row stride 64 elems; slot g' = g ^ ((row>>1)&7) -> ds_read_b128 2-way max.
// headBits: blockIdx.z = zb*2 + h; per-head offsets hA/hB/hC.
// ---------------------------------------------------------------------------
__global__ __launch_bounds__(256)
void bgemm_k(GSeg s0, GSeg s1, GSeg s2,
             const float* __restrict__ bias,
             const u16* __restrict__ residH, const u16* __restrict__ residL,
             const float* __restrict__ rsc, const float* __restrict__ csc,
             float* __restrict__ Cf, u16* __restrict__ Cb, u16* __restrict__ Cb2,
             int ldc, long sC, int hC, int headBits, int sS,
             float alpha, int flags, int Mstore)
{
  const int zAll = blockIdx.z;
  const int hIdx = headBits ? (zAll & 1) : 0;
  const int z    = headBits ? (zAll >> 1) : zAll;
  const long cofs = (long)z * sC + (long)hIdx * hC;
  const float* rs = rsc ? rsc + (long)z * sS : nullptr;
  const float* cs = csc ? csc + (long)z * sS : nullptr;

  __shared__ u16 As[2][128 * 64];
  __shared__ u16 Bs[2][128 * 64];

  const int tid  = threadIdx.x;
  const int wave = tid >> 6, lane = tid & 63;
  const int m0 = blockIdx.x * 128, n0 = blockIdx.y * 128;
  const int wrow = (wave >> 1) * 64, wcol = (wave & 1) * 64;

  // per-segment resolved base pointers + iteration split
  const u16* ApS[3]; const u16* BpS[3]; int ldaS[3], ldbS[3];
  ApS[0] = s0.A + (long)z * s0.sA + (long)hIdx * s0.hA;
  BpS[0] = s0.B + (long)z * s0.sB + (long)hIdx * s0.hB;
  ldaS[0] = s0.lda; ldbS[0] = s0.ldb;
  ApS[1] = s1.A ? s1.A + (long)z * s1.sA + (long)hIdx * s1.hA : nullptr;
  BpS[1] = s1.B ? s1.B + (long)z * s1.sB + (long)hIdx * s1.hB : nullptr;
  ldaS[1] = s1.lda; ldbS[1] = s1.ldb;
  ApS[2] = s2.A ? s2.A + (long)z * s2.sA + (long)hIdx * s2.hA : nullptr;
  BpS[2] = s2.B ? s2.B + (long)z * s2.sB + (long)hIdx * s2.hB : nullptr;
  ldaS[2] = s2.lda; ldbS[2] = s2.ldb;
  const int n0i = s0.K >> 6, n1i = n0i + (s1.K >> 6);
  const int nIt = n1i + (s2.K >> 6);

  // staging geometry: wave stages rows [wave*32, wave*32+32) of A and B;
  // one glds inst = 8 rows x 8 groups (64 lanes x 16B = 1KB).
  const int lrow = lane >> 3;          // 0..7
  const int lgrp = lane & 7;           // 0..7

  facc acc[4][4];
#pragma unroll
  for (int i = 0; i < 4; ++i)
#pragma unroll
    for (int j = 0; j < 4; ++j) acc[i][j] = (facc)(0.f);

  const int r16 = lane & 15, gq = lane >> 4;

  // stage iteration `it` into buffer `buf`
  auto stage = [&](int buf, int it) {
    int sidx, base;
    if (it < n0i)      { sidx = 0; base = 0; }
    else if (it < n1i) { sidx = 1; base = n0i; }
    else               { sidx = 2; base = n1i; }
    const int k0 = (it - base) << 6;
    const u16* Ab = ApS[sidx];
    const u16* Bb = BpS[sidx];
    const int la = ldaS[sidx], lb = ldbS[sidx];
#pragma unroll
    for (int ss = 0; ss < 4; ++ss) {
      int rloc = wave * 32 + ss * 8;
      int row  = rloc + lrow;
      int g    = lgrp ^ ((row >> 1) & 7);
      __builtin_amdgcn_global_load_lds(
          (gaddr_t)(const void*)(Ab + (long)(m0 + row) * la + k0 + g * 8),
          (laddr_t)(As[buf] + rloc * 64), 16, 0, 0);
      __builtin_amdgcn_global_load_lds(
          (gaddr_t)(const void*)(Bb + (long)(n0 + row) * lb + k0 + g * 8),
          (laddr_t)(Bs[buf] + rloc * 64), 16, 0, 0);
    }
  };

  stage(0, 0);
  for (int it = 0; it < nIt; ++it) {
    const int buf = it & 1;
    __syncthreads();                      // drains glds for buf; prev reads done
    if (it + 1 < nIt) stage(buf ^ 1, it + 1);

#pragma unroll
    for (int kk = 0; kk < 2; ++kk) {
      bfrag af[4], bb[4];
#pragma unroll
      for (int mt = 0; mt < 4; ++mt) {
        int r = wrow + mt * 16 + r16;
        int slot = (kk * 4 + gq) ^ ((r >> 1) & 7);
        af[mt] = *(const bfrag*)&As[buf][r * 64 + slot * 8];
      }
#pragma unroll
      for (int nt = 0; nt < 4; ++nt) {
        int r = wcol + nt * 16 + r16;
        int slot = (kk * 4 + gq) ^ ((r >> 1) & 7);
        bb[nt] = *(const bfrag*)&Bs[buf][r * 64 + slot * 8];
      }
#pragma unroll
      for (int mt = 0; mt < 4; ++mt)
#pragma unroll
        for (int nt = 0; nt < 4; ++nt)
          acc[mt][nt] = __builtin_amdgcn_mfma_f32_16x16x32_bf16(
              af[mt], bb[nt], acc[mt][nt], 0, 0, 0);
    }
  }

  // epilogue: C/D layout col = lane&15, row = (lane>>4)*4 + reg
#pragma unroll
  for (int mt = 0; mt < 4; ++mt) {
#pragma unroll
    for (int nt = 0; nt < 4; ++nt) {
#pragma unroll
      for (int r = 0; r < 4; ++r) {
        int gm = m0 + wrow + mt * 16 + gq * 4 + r;
        int gn = n0 + wcol + nt * 16 + r16;
        if (gm >= Mstore) continue;
        float v = acc[mt][nt][r] * alpha;
        long ci = cofs + (long)gm * ldc + gn;
        if (flags & F_SIMSC)  v *= rs[gm] * cs[gn];
        if (flags & F_ROWSC)  v *= rs[gm];
        if (bias)             v += bias[gn];
        if (flags & F_RESID2) v += bf2f(residH[ci]) + bf2f(residL[ci]);
        if (flags & F_RELU)   v = fmaxf(v, 0.f);
        if (Cf) Cf[ci] = v;
        if (Cb) {
          u16 hv = f2bf(v);
          Cb[ci] = hv;
          if (Cb2) Cb2[ci] = f2bf(v - bf2f(hv));
        }
      }
    }
  }
}

// ---------------------------------------------------------------------------
__global__ __launch_bounds__(256)
void castbf_k(const float* __restrict__ in, u16* __restrict__ out, int n)
{
  int i = blockIdx.x * 256 + threadIdx.x;
  if (i < n) out[i] = f2bf(in[i]);
}

// all 7 weight matrices in one launch (layout matches wgt arena)
__global__ __launch_bounds__(256)
void castw_k(const float* w0, const float* w1, const float* w2,
             const float* w3, const float* w4, const float* w5,
             const float* w6, u16* __restrict__ dst)
{
  int i = blockIdx.x * 256 + threadIdx.x;
  const float* s; int off;
  if      (i < 262144)  { s = w0; off = 0; }
  else if (i < 1048576) { s = w1; off = 262144; }
  else if (i < 1310720) { s = w2; off = 1048576; }
  else if (i < 1835008) { s = w3; off = 1310720; }
  else if (i < 2359296) { s = w4; off = 1835008; }
  else if (i < 2883584) { s = w5; off = 2359296; }
  else                  { s = w6; off = 2883584; }
  dst[i] = f2bf(s[i - off]);
}

// x1 = LN(bf16 a + bf16 b) -> hi (in place over a ok) + lo
__global__ __launch_bounds__(256)
void ln1_k(const u16* __restrict__ a, const u16* __restrict__ b,
           const float* __restrict__ g, const float* __restrict__ be,
           u16* __restrict__ oh, u16* __restrict__ ol)
{
  long base = (long)blockIdx.x * 512;
  int t = threadIdx.x;
  float v0 = bf2f(a[base + t])       + bf2f(b[base + t]);
  float v1 = bf2f(a[base + t + 256]) + bf2f(b[base + t + 256]);
  __shared__ float red[4], red2[4];
  float s = wsum(v0 + v1);
  if ((t & 63) == 0) red[t >> 6] = s;
  __syncthreads();
  float mean = (red[0] + red[1] + red[2] + red[3]) * (1.f / 512.f);
  float c0 = v0 - mean, c1 = v1 - mean;
  float ss = wsum(c0 * c0 + c1 * c1);
  if ((t & 63) == 0) red2[t >> 6] = ss;
  __syncthreads();
  float var = (red2[0] + red2[1] + red2[2] + red2[3]) * (1.f / 512.f);
  float rstd = rsqrtf(var + 1e-5f);
  float o0 = c0 * rstd * g[t]       + be[t];
  float o1 = c1 * rstd * g[t + 256] + be[t + 256];
  u16 h0 = f2bf(o0), h1 = f2bf(o1);
  oh[base + t] = h0;       oh[base + t + 256] = h1;
  ol[base + t] = f2bf(o0 - bf2f(h0));
  ol[base + t + 256] = f2bf(o1 - bf2f(h1));
}

// x2 = LN((hi+lo) + bf16 b) -> bf16
__global__ __launch_bounds__(256)
void ln2_k(const u16* __restrict__ hi, const u16* __restrict__ lo,
           const u16* __restrict__ b, const float* __restrict__ g,
           const float* __restrict__ be, u16* __restrict__ ob)
{
  long base = (long)blockIdx.x * 512;
  int t = threadIdx.x;
  float v0 = bf2f(hi[base + t])       + bf2f(lo[base + t])       + bf2f(b[base + t]);
  float v1 = bf2f(hi[base + t + 256]) + bf2f(lo[base + t + 256]) + bf2f(b[base + t + 256]);
  __shared__ float red[4], red2[4];
  float s = wsum(v0 + v1);
  if ((t & 63) == 0) red[t >> 6] = s;
  __syncthreads();
  float mean = (red[0] + red[1] + red[2] + red[3]) * (1.f / 512.f);
  float c0 = v0 - mean, c1 = v1 - mean;
  float ss = wsum(c0 * c0 + c1 * c1);
  if ((t & 63) == 0) red2[t >> 6] = ss;
  __syncthreads();
  float var = (red2[0] + red2[1] + red2[2] + red2[3]) * (1.f / 512.f);
  float rstd = rsqrtf(var + 1e-5f);
  ob[base + t]       = f2bf(c0 * rstd * g[t]       + be[t]);
  ob[base + t + 256] = f2bf(c1 * rstd * g[t + 256] + be[t + 256]);
}

// invn[row] = 1/max(||hi+lo||, 1e-12)
__global__ __launch_bounds__(256)
void rownorm_k(const u16* __restrict__ hi, const u16* __restrict__ lo,
               float* __restrict__ invn)
{
  long base = (long)blockIdx.x * 512;
  int t = threadIdx.x;
  float v0 = bf2f(hi[base + t])       + bf2f(lo[base + t]);
  float v1 = bf2f(hi[base + t + 256]) + bf2f(lo[base + t + 256]);
  __shared__ float red[4];
  float s = wsum(v0 * v0 + v1 * v1);
  if ((t & 63) == 0) red[t >> 6] = s;
  __syncthreads();
  if (t == 0) {
    float tot = red[0] + red[1] + red[2] + red[3];
    invn[blockIdx.x] = 1.f / fmaxf(sqrtf(tot), 1e-12f);
  }
}

// in-place row softmax over 1024 bf16
__global__ __launch_bounds__(256)
void softmaxu_k(u16* __restrict__ sc)
{
  long row = blockIdx.x;
  u16* p = sc + row * 1024;
  int t = threadIdx.x;
  float v[4];
#pragma unroll
  for (int i = 0; i < 4; ++i) v[i] = bf2f(p[t + 256 * i]);
  __shared__ float redm[4], redsum[4];
  float m4 = fmaxf(fmaxf(v[0], v[1]), fmaxf(v[2], v[3]));
  float wm = wmaxf(m4);
  if ((t & 63) == 0) redm[t >> 6] = wm;
  __syncthreads();
  float MX = fmaxf(fmaxf(redm[0], redm[1]), fmaxf(redm[2], redm[3]));
  float s = 0.f;
#pragma unroll
  for (int i = 0; i < 4; ++i) { v[i] = __expf(v[i] - MX); s += v[i]; }
  float ws_ = wsum(s);
  if ((t & 63) == 0) redsum[t >> 6] = ws_;
  __syncthreads();
  float inv = 1.f / (redsum[0] + redsum[1] + redsum[2] + redsum[3]);
#pragma unroll
  for (int i = 0; i < 4; ++i) p[t + 256 * i] = f2bf(v[i] * inv);
}

// 64x64 tiled u16 transpose; z = zb*2+h when headBits
__global__ __launch_bounds__(256)
void transp_k(const u16* __restrict__ in, u16* __restrict__ out,
              int inStride, int outStride, long sIn, long sOut,
              int hIn, int headBits)
{
  const int zAll = blockIdx.z;
  const int h  = headBits ? (zAll & 1) : 0;
  const int zb = headBits ? (zAll >> 1) : zAll;
  const u16* src = in + (long)zb * sIn + (long)h * hIn;
  u16* dst = out + (long)zAll * sOut;
  const int r0 = blockIdx.x * 64, c0 = blockIdx.y * 64;
  __shared__ u16 tile[64][66];
  const int t = threadIdx.x;
#pragma unroll
  for (int p = 0; p < 16; ++p) {
    int idx = p * 256 + t;
    int r = idx >> 6, c = idx & 63;
    tile[r][c] = src[(long)(r0 + r) * inStride + c0 + c];
  }
  __syncthreads();
#pragma unroll
  for (int p = 0; p < 16; ++p) {
    int idx = p * 256 + t;
    int c = idx >> 6, r = idx & 63;
    dst[(long)(c0 + c) * outStride + r0 + r] = tile[r][c];
  }
}

// per-row top-4 (descending, ties -> lower index, matching lax.top_k)
__global__ __launch_bounds__(64)
void topk_k(const float* __restrict__ sim, int* __restrict__ idx4)
{
  long row = blockIdx.x;
  const float* p = sim + row * 1024;
  int t = threadIdx.x;
  int c0 = -1, c1 = -1, c2 = -1, c3 = -1;
#pragma unroll
  for (int pass = 0; pass < 4; ++pass) {
    float best = -INFINITY;
    int bi = 1 << 30;
    for (int j = t; j < 1024; j += 64) {
      if (j == c0 || j == c1 || j == c2 || j == c3) continue;
      float v = p[j];
      if (v > best || (v == best && j < bi)) { best = v; bi = j; }
    }
#pragma unroll
    for (int off = 32; off; off >>= 1) {
      float ov = __shfl_down(best, off);
      int   oi = __shfl_down(bi, off);
      if (ov > best || (ov == best && oi < bi)) { best = ov; bi = oi; }
    }
    bi = __shfl(bi, 0);
    if (pass == 0) c0 = bi; else if (pass == 1) c1 = bi;
    else if (pass == 2) c2 = bi; else c3 = bi;
  }
  if (t == 0) { int* q = idx4 + row * 4; q[0] = c0; q[1] = c1; q[2] = c2; q[3] = c3; }
}

// adjacency -> bf16 + invcnt, from fp32 sim chunk (chunk-local rows)
__global__ __launch_bounds__(256)
void adjbf_k(const float* __restrict__ sim, const int* __restrict__ idx4,
             u16* __restrict__ adjb, float* __restrict__ invcnt)
{
  long row = blockIdx.x;
  int b = (int)(row >> 10);
  int i = (int)(row & 1023);
  const float* prow = sim + row * 1024;
  u16* arow_ = adjb + row * 1024;
  const int* my = idx4 + row * 4;
  int m0 = my[0], m1 = my[1], m2 = my[2], m3 = my[3];
  int t = threadIdx.x;
  float lsum = 0.f;
  for (int j = t; j < 1024; j += 256) {
    float v = prow[j];
    bool present = false;
    if (j != i) {
      present = (j == m0) | (j == m1) | (j == m2) | (j == m3);
      if (!present) {
        const int* oj = idx4 + (((long)b << 10) + j) * 4;
        present = (oj[0] == i) | (oj[1] == i) | (oj[2] == i) | (oj[3] == i);
      }
    }
    float a = present ? v : 0.f;
    arow_[j] = f2bf(a);
    lsum += a;
  }
  __shared__ float red[4];
  float s = wsum(lsum);
  if ((t & 63) == 0) red[t >> 6] = s;
  __syncthreads();
  if (t == 0) {
    float tot = red[0] + red[1] + red[2] + red[3];
    invcnt[row] = 1.f / fmaxf(tot, 1.f);
  }
}

// pooled_bf[128][512]: rows<32 = mean_s x2_bf, rows>=32 = 0
__global__ __launch_bounds__(256)
void poolbf_k(const u16* __restrict__ x2, u16* __restrict__ pooled)
{
  int i = blockIdx.x * 256 + threadIdx.x;   // 0..65535
  int b = i >> 9, d = i & 511;
  float s = 0.f;
  if (b < 32) {
    const u16* p = x2 + ((long)b << 10) * 512 + d;
    for (int sdx = 0; sdx < 1024; ++sdx) s += bf2f(p[(long)sdx * 512]);
    s *= (1.f / 1024.f);
  }
  pooled[i] = f2bf(s);
}

// ---------------------------------------------------------------------------
static inline GSeg mkseg(const u16* A, const u16* B, int K, int lda, int ldb,
                         long sA = 0, long sB = 0, int hA = 0, int hB = 0)
{
  GSeg s; s.A = A; s.B = B; s.K = K; s.lda = lda; s.ldb = ldb;
  s.sA = sA; s.sB = sB; s.hA = hA; s.hB = hB; return s;
}

static inline void bgemm(hipStream_t st, GSeg s0, GSeg s1, GSeg s2,
    const float* bias, const u16* residH, const u16* residL,
    const float* rsc, const float* csc, float* Cf, u16* Cb, u16* Cb2,
    int M, int N, int ldc, long sC, int hC, int headBits, int sS,
    float alpha, int flags, int nz, int Mstore = -1)
{
  dim3 g(M / 128, N / 128, nz);
  bgemm_k<<<g, 256, 0, st>>>(s0, s1, s2, bias, residH, residL,
                             rsc, csc, Cf, Cb, Cb2, ldc, sC, hC, headBits,
                             sS, alpha, flags, Mstore < 0 ? M : Mstore);
}

extern "C" void kernel_launch(void* const* d_in, const int* in_sizes, int n_in,
                              void* d_out, int out_size, void* d_ws, size_t ws_size,
                              hipStream_t stream)
{
  (void)in_sizes; (void)n_in; (void)out_size;
  const float* x     = (const float*)d_in[0];
  const float* enc_w = (const float*)d_in[1];
  const float* enc_b = (const float*)d_in[2];
  const float* in_w  = (const float*)d_in[3];
  const float* in_b  = (const float*)d_in[4];
  const float* out_w = (const float*)d_in[5];
  const float* out_b = (const float*)d_in[6];
  const float* ln1_g = (const float*)d_in[7];
  const float* ln1_b = (const float*)d_in[8];
  const float* fw1   = (const float*)d_in[9];
  const float* fb1   = (const float*)d_in[10];
  const float* fw2   = (const float*)d_in[11];
  const float* fb2   = (const float*)d_in[12];
  const float* gc_w  = (const float*)d_in[13];
  const float* gc_b  = (const float*)d_in[14];
  const float* ln2_g = (const float*)d_in[15];
  const float* ln2_b = (const float*)d_in[16];
  const float* dec_w = (const float*)d_in[17];
  const float* dec_b = (const float*)d_in[18];
  float* out = (float*)d_out;

  // ---- arena ----
  char* base = (char*)d_ws;
  u16*  bf1  = (u16*)(base);                  // h_bf -> x1_hi (in place)
  u16*  lob  = (u16*)(base + 33554432);       // x1_lo
  u16*  bf2  = (u16*)(base + 67108864);       // ctx -> nsum -> x2
  u16*  wgt  = (u16*)(base + 100663296);      // bf16 weights
  float* invn    = (float*)(base + 106954752);
  float* invcnt  = (float*)(base + 107085824);
  u16*   pooledb = (u16*)(base + 107216896);
  int*   idx4    = (int*)(base + 107347968);
  char*  scr     = base + 107872256;          // 80MB scratch, phase-multiplexed
  const size_t need = 107872256 + 83886080;
  if (ws_size < need) return;

  u16* encw = wgt;
  u16* inw  = wgt + 262144;
  u16* outw = wgt + 1048576;
  u16* fw1b = wgt + 1310720;
  u16* fw2b = wgt + 1835008;
  u16* gcwb = wgt + 2359296;
  u16* decw = wgt + 2883584;

  const int Mtok = 32768;
  GSeg Z = mkseg(nullptr, nullptr, 0, 0, 0);

  // ---- casts ----
  u16* xbf = (u16*)scr;
  castbf_k<<<65536, 256, 0, stream>>>(x, xbf, 16777216);
  castw_k<<<12288, 256, 0, stream>>>(enc_w, in_w, out_w, fw1, fw2, gc_w, dec_w, wgt);

  // 1. h_bf = relu(x @ enc_w^T + enc_b)
  bgemm(stream, mkseg(xbf, encw, 512, 512, 512), Z, Z,
        enc_b, nullptr, nullptr, nullptr, nullptr, nullptr, bf1, nullptr,
        Mtok, 512, 512, 0, 0, 0, 0, 1.f, F_RELU, 1);

  // 2+3. attention: 4 chunks x 8 batches, heads folded into z (z=16)
  for (int c = 0; c < 4; ++c) {
    long row0 = (long)c * 8192;
    u16* qkvc = (u16*)scr;                        // 8192x1536 u16 (24MB)
    u16* sco  = (u16*)(scr + 25165824);           // 16 x 1024x1024 u16 (32MB)
    u16* vT   = (u16*)(scr + 58720256);           // 16 x 256x1024 u16 (8MB)
    bgemm(stream, mkseg(bf1 + row0 * 512, inw, 512, 512, 512), Z, Z,
          in_b, nullptr, nullptr, nullptr, nullptr, nullptr, qkvc, nullptr,
          8192, 1536, 1536, 0, 0, 0, 0, 1.f, 0, 1);
    // scores[z=16] = 1/16 * Q @ K^T  -> bf16
    bgemm(stream, mkseg(qkvc, qkvc + 512, 256, 1536, 1536,
                        1572864, 1572864, 256, 256), Z, Z,
          nullptr, nullptr, nullptr, nullptr, nullptr, nullptr, sco, nullptr,
          1024, 1024, 1024, 2097152, 1048576, 1, 0, 0.0625f, 0, 16);
    softmaxu_k<<<16384, 256, 0, stream>>>(sco);
    transp_k<<<dim3(16, 4, 16), 256, 0, stream>>>(
        qkvc + 1024, vT, 1536, 1024, 1572864, 262144, 256, 1);
    // ctx = P @ V  (B = V^T rows = d, cols = s)
    bgemm(stream, mkseg(sco, vT, 1024, 1024, 1024,
                        2097152, 524288, 1048576, 262144), Z, Z,
          nullptr, nullptr, nullptr, nullptr, nullptr, nullptr,
          bf2 + row0 * 512, nullptr,
          1024, 256, 512, 524288, 256, 1, 0, 1.f, 0, 16);
  }

  // 4. attn_out -> bf16
  u16* aoc = (u16*)scr;                           // 32MB
  bgemm(stream, mkseg(bf2, outw, 512, 512, 512), Z, Z,
        out_b, nullptr, nullptr, nullptr, nullptr, nullptr, aoc, nullptr,
        Mtok, 512, 512, 0, 0, 0, 0, 1.f, 0, 1);

  // 5. x1 = LN(h + attn_out) -> hi (in place) + lo
  ln1_k<<<Mtok, 256, 0, stream>>>(bf1, aoc, ln1_g, ln1_b, bf1, lob);

  // 6+7. FFN
  u16* mid = (u16*)scr;                           // 64MB
  bgemm(stream, mkseg(bf1, fw1b, 512, 512, 512), Z, Z,
        fb1, nullptr, nullptr, nullptr, nullptr, nullptr, mid, nullptr,
        Mtok, 1024, 1024, 0, 0, 0, 0, 1.f, F_RELU, 1);
  bgemm(stream, mkseg(mid, fw2b, 1024, 1024, 1024), Z, Z,
        fb2, bf1, lob, nullptr, nullptr, nullptr, bf1, lob,
        Mtok, 512, 512, 0, 0, 0, 0, 1.f, F_RESID2, 1);

  // 8. row norms
  rownorm_k<<<Mtok, 256, 0, stream>>>(bf1, lob, invn);

  // 9-12. graph: x1T once, then 4 chunks x 8 batches
  float* simc = (float*)scr;                      // 32MB
  u16*   adjb = (u16*)(scr + 33554432);           // 16MB
  u16*   x1T  = (u16*)(scr + 50331648);           // 32MB (all 32 batches)
  transp_k<<<dim3(16, 8, 32), 256, 0, stream>>>(bf1, x1T, 512, 1024,
                                                524288, 524288, 0, 0);
  for (int g = 0; g < 4; ++g) {
    long row0 = (long)g * 8192;
    // sim = (hi.hi^T) * invn_i * invn_j  (bf16 inputs, fp32 acc)
    bgemm(stream,
          mkseg(bf1 + row0 * 512, bf1 + row0 * 512, 512, 512, 512, 524288, 524288),
          Z, Z, nullptr, nullptr, nullptr, invn + row0, invn + row0,
          simc, nullptr, nullptr,
          1024, 1024, 1024, 1048576, 0, 0, 1024, 1.f, F_SIMSC, 8);
    topk_k<<<8192, 64, 0, stream>>>(simc, idx4 + row0 * 4);
    adjbf_k<<<8192, 256, 0, stream>>>(simc, idx4 + row0 * 4, adjb, invcnt + row0);
    // nsum = (adj @ x1) * invcnt
    bgemm(stream, mkseg(adjb, x1T + row0 * 512, 1024, 1024, 1024,
                        1048576, 524288), Z, Z,
          nullptr, nullptr, nullptr, invcnt + row0, nullptr, nullptr,
          bf2 + row0 * 512, nullptr,
          1024, 512, 512, 524288, 0, 0, 1024, 1.f, F_ROWSC, 8);
  }

  // 13/14. gcout = x1_hi @ gcW1^T + nsum @ gcW2^T + gc_b  (2-seg) -> bf16
  u16* gch = (u16*)scr;                           // 32MB
  bgemm(stream, mkseg(bf1, gcwb, 512, 512, 1024),
        mkseg(bf2, gcwb + 512, 512, 512, 1024), Z,
        gc_b, nullptr, nullptr, nullptr, nullptr, nullptr, gch, nullptr,
        Mtok, 512, 512, 0, 0, 0, 0, 1.f, 0, 1);

  // 15. x2 = LN(x1 + gcout) -> bf16 (over bf2; nsum consumed)
  ln2_k<<<Mtok, 256, 0, stream>>>(bf1, lob, gch, ln2_g, ln2_b, bf2);

  // 16+17. pool + decoder
  poolbf_k<<<256, 256, 0, stream>>>(bf2, pooledb);
  bgemm(stream, mkseg(pooledb, decw, 512, 512, 512), Z, Z,
        dec_b, nullptr, nullptr, nullptr, nullptr, out, nullptr, nullptr,
        128, 512, 512, 0, 0, 0, 0, 1.f, 0, 1, 32);
}